// Round 16
// baseline (146.688 us; speedup 1.0000x reference)
//
#include <hip/hip_runtime.h>
#include <hip/hip_bf16.h>

#define BB 4
#define CC 64
#define HH 128
#define WW 128
#define HW (HH * WW)
#define TOTPIX (BB * HW)  // 65536

typedef short bf16x8 __attribute__((ext_vector_type(8)));
typedef float f32x4 __attribute__((ext_vector_type(4)));

static __device__ __forceinline__ short f2bf(float f) {
  __hip_bfloat16 h = __float2bfloat16(f);
  return __builtin_bit_cast(short, h);
}
static __device__ __forceinline__ float bf2f(short s) {
  unsigned int u = ((unsigned int)(unsigned short)s) << 16;
  return __builtin_bit_cast(float, u);
}

// async 16B/lane global -> LDS (wave-uniform LDS base + lane*16)
static __device__ __forceinline__ void stage1k(const short* g, short* lds) {
  __builtin_amdgcn_global_load_lds(
      (const __attribute__((address_space(1))) unsigned int*)g,
      (__attribute__((address_space(3))) unsigned int*)lds, 16, 0, 0);
}

// NCHW f32 -> NHWC bf16 for two tensors. Block = 64 px x 64 c tile.
__global__ __launch_bounds__(256) void cast_nhwc_kernel(
    const float* __restrict__ a, const float* __restrict__ b,
    short* __restrict__ oa, short* __restrict__ ob) {
  __shared__ float tile[64][68];
  const int bid = blockIdx.x;        // 1024 blocks
  const int bb = bid >> 8;           // batch
  const int hw0 = (bid & 255) * 64;  // 64-px stripe
  const int t = threadIdx.x;
  for (int s = 0; s < 2; s++) {
    const float* src = s ? b : a;
    short* dst = s ? ob : oa;
    if (s) __syncthreads();
    {
      const int lp = t & 15;  // 16 lanes x float4 = 64 px
      for (int c = (t >> 4); c < 64; c += 16) {
        float4 v = *(const float4*)&src[((size_t)(bb * 64 + c)) * HW + hw0 + lp * 4];
        *(float4*)&tile[c][lp * 4] = v;
      }
    }
    __syncthreads();
    {
      const int px = t >> 2;
      const int seg = t & 3;
      bf16x8 s0, s1;
#pragma unroll
      for (int i = 0; i < 8; i++) s0[i] = f2bf(tile[seg * 16 + i][px]);
#pragma unroll
      for (int i = 0; i < 8; i++) s1[i] = f2bf(tile[seg * 16 + 8 + i][px]);
      short* dp = dst + ((size_t)(bid * 64 + px)) * 64 + seg * 16;
      *(bf16x8*)dp = s0;
      *(bf16x8*)(dp + 8) = s1;
    }
  }
}

// Weight prep, all 3 stages in one launch (stage = blockIdx.x/144).
__global__ __launch_bounds__(256) void prep_weights_all(
    const float* __restrict__ wd1, const float* __restrict__ wo1,
    short* __restrict__ wtd1, short* __restrict__ wtoff1,
    const float* __restrict__ wd2, const float* __restrict__ wo2,
    short* __restrict__ wtd2, short* __restrict__ wtoff2,
    const float* __restrict__ wd3, const float* __restrict__ wo3,
    short* __restrict__ wtd3, short* __restrict__ wtoff3) {
  const int s = blockIdx.x / 144;
  const float* wd = (s == 0) ? wd1 : (s == 1) ? wd2 : wd3;
  const float* wo = (s == 0) ? wo1 : (s == 1) ? wo2 : wo3;
  short* wtd = (s == 0) ? wtd1 : (s == 1) ? wtd2 : wtd3;
  short* wtoff = (s == 0) ? wtoff1 : (s == 1) ? wtoff2 : wtoff3;
  const int i = (blockIdx.x % 144) * 256 + threadIdx.x;  // 0..36863
  const int j = i & 7, l = (i >> 3) & 63, f = i >> 9;
  {
    int ot = f & 3, cf = (f >> 2) & 1, k = f >> 3;
    int o = ot * 16 + (l & 15), c = cf * 32 + (l >> 4) * 8 + j;
    wtd[i] = f2bf(wd[(o * 64 + c) * 9 + k]);
  }
  {
    int ot = f & 1, ks = f >> 1;
    int cs = ks & 3, k = ks >> 2;
    int o = ot * 16 + (l & 15), c = cs * 32 + (l >> 4) * 8 + j;
    wtoff[i] = (o < 18) ? f2bf(wo[(o * 128 + c) * 9 + k]) : (short)0;
  }
}

// ---------- LDS-tiled MFMA offset conv (r14, unchanged) ----------
__global__ __launch_bounds__(256, 4) void off_tile_kernel(
    const short* __restrict__ ref, const short* __restrict__ x2,
    const short* __restrict__ wtoff, const float* __restrict__ bias,
    float* __restrict__ out) {
  __shared__ short tile[2 * 6 * 24 * 64];  // [tensor][row][px][64ch]
  int bid = blockIdx.x;
  bid = (bid & 7) * (gridDim.x >> 3) + (bid >> 3);  // 1024 % 8 == 0
  const int tid = threadIdx.x;
  const int l = tid & 63;
  const int g = __builtin_amdgcn_readfirstlane(tid >> 6);  // row-group 0..3
  const int col = l & 15, quad = l >> 4;
  const int b = bid >> 8;
  const int rem = bid & 255;
  const int h0 = (rem >> 3) * 4;   // 32 row-tiles
  const int w0 = (rem & 7) * 16;   // 8 col-tiles
  const int oy = h0 - 1, ox = w0 - 1;
  const int h = h0 + g, w = w0 + col;
  const int pix = ((b << 7) + h) * WW + w;

  const short* srcs[2] = {ref + (size_t)b * (HW * 64), x2 + (size_t)b * (HW * 64)};

  {
    const int tc = l >> 3;  // px-in-chunk 0..7
    const int m = l & 7;    // dest slot
#pragma unroll
    for (int i = 0; i < 9; i++) {
      const int idx = g + i * 4;        // 0..35, wave-uniform
      const int t = idx / 18;
      const int rr = (idx % 18) / 3, seg = idx % 3;
      const int iy = min(max(oy + rr, 0), HH - 1);
      const int tcol = seg * 8 + tc;
      const int ix = min(max(ox + tcol, 0), WW - 1);
      const int sc = (m - tcol) & 7;
      stage1k(srcs[t] + (((iy << 7) + ix) << 6) + sc * 8,
              &tile[((t * 6 + rr) * 24 + seg * 8) << 6]);
    }
  }

  f32x4 acc0 = {0.f, 0.f, 0.f, 0.f}, acc1 = {0.f, 0.f, 0.f, 0.f};
  const bf16x8* wp = (const bf16x8*)wtoff + l;

  __syncthreads();  // tile staged

#pragma unroll
  for (int k = 0; k < 9; k++) {
    const int ky = k / 3, kx = k - ky * 3;
    const int hh = h + ky - 1, ww2 = w + kx - 1;
    const bool valid = (hh >= 0) & (hh < HH) & (ww2 >= 0) & (ww2 < WW);
    const int tr = g + ky;      // 0..5
    const int tcx = col + kx;   // 0..17
#pragma unroll
    for (int cs = 0; cs < 4; cs++) {
      const int t = cs >> 1;
      const int chunk = (cs & 1) * 4 + quad;  // 0..7 within pixel
      bf16x8 v = *(const bf16x8*)&tile[(((t * 6 + tr) * 24 + tcx) << 6) +
                                       (((chunk + tcx) & 7) << 3)];
      if (!valid) v = (bf16x8)(short)0;
      const int f = (k * 4 + cs) * 2;
      acc0 = __builtin_amdgcn_mfma_f32_16x16x32_bf16(wp[f * 64], v, acc0, 0, 0, 0);
      acc1 = __builtin_amdgcn_mfma_f32_16x16x32_bf16(wp[(f + 1) * 64], v, acc1, 0, 0, 0);
    }
  }

  // planar output: out[o][pix], coalesced 64B stores
#pragma unroll
  for (int r = 0; r < 4; r++)
    out[(quad * 4 + r) * TOTPIX + pix] = acc0[r] + bias[quad * 4 + r];
  if (quad == 0) {
    out[16 * TOTPIX + pix] = acc1[0] + bias[16];
    out[17 * TOTPIX + pix] = acc1[1] + bias[17];
  }
}

// ---------- LDS-tiled MFMA deformable conv, precomputed addresses ----------
// Block = 512 thr = 8 row-waves; output tile 8x16 px; halo 16x24 px (49KB).
// All 9 taps' addresses + bilinear weights precomputed into registers
// (static-indexed, fully unrolled); main loop is pure ds_read->blend->MFMA
// with no address dependency, so the compiler can pipeline taps.
// launch_bounds(512,2): grid caps residency at 2 blocks/CU, VGPR cap 128 free.
#define TH 16
#define TWP 24
__global__ __launch_bounds__(512, 2) void deform_tile_kernel(
    const short* __restrict__ x, const float* __restrict__ off,
    const short* __restrict__ wtd, const float* __restrict__ bias,
    float* __restrict__ outf, short* __restrict__ outb) {
  __shared__ short tile[TH * TWP * 64];  // 49152 B
  int bid = blockIdx.x;
  bid = (bid & 7) * (gridDim.x >> 3) + (bid >> 3);  // 512 % 8 == 0
  const int tid = threadIdx.x;
  const int l = tid & 63;
  const int wv = __builtin_amdgcn_readfirstlane(tid >> 6);  // 0..7
  const int col = l & 15, quad = l >> 4;
  const int b = bid >> 7;
  const int rem = bid & 127;
  const int h0 = (rem >> 3) * 8;   // 16 row-tiles
  const int w0 = (rem & 7) * 16;   // 8 col-tiles
  const int oy = h0 - 4, ox = w0 - 4;
  const int h = h0 + wv, w = w0 + col;
  const int pix = ((b << 7) + h) * WW + w;

  const short* xb = x + (size_t)b * (HW * 64);

  // ---- stage 16x24-px halo tile, chunk-swizzled source ----
  {
    const int tc = ((l >> 3) & 7);
    const int m = l & 7;
#pragma unroll
    for (int i = 0; i < 6; i++) {
      const int idx = wv + i * 8;        // 0..47
      const int r = idx / 3, seg = idx % 3;
      const int iy = min(max(oy + r, 0), HH - 1);
      const int tcol = seg * 8 + tc;
      const int ix = min(max(ox + tcol, 0), WW - 1);
      const int sc = (m - tcol) & 7;
      stage1k(xb + (((iy << 7) + ix) << 6) + sc * 8,
              &tile[((r * TWP + seg * 8) << 6)]);
    }
  }

  // planar offsets: off[j][pix], 18 coalesced dword loads
  float offv[18];
#pragma unroll
  for (int j = 0; j < 18; j++) offv[j] = off[j * TOTPIX + pix];

  const int c0g = quad * 8;

  // ---- precompute: per-tap offsets (short units) + weights + LDS-mask ----
  // Chunk-B address = chunk-A address ^ 32 (slot XOR-4 identity), both paths.
  int t0[9], t1[9], t2[9], t3[9];
  float w0_[9], w1_[9], w2_[9], w3_[9];
  unsigned lmask = 0;
#pragma unroll
  for (int k = 0; k < 9; k++) {
    const int ky = k / 3, kx = k - ky * 3;
    const float py = (float)(h - 1 + ky) + offv[2 * k];
    const float pxx = (float)(w - 1 + kx) + offv[2 * k + 1];
    const float y0f = floorf(py), x0f = floorf(pxx);
    const float ly = py - y0f, lx = pxx - x0f;
    const int y0 = (int)y0f, x0 = (int)x0f;
    const int y1 = y0 + 1, x1 = x0 + 1;
    float w00 = (1.f - ly) * (1.f - lx), w01 = (1.f - ly) * lx;
    float w10 = ly * (1.f - lx), w11 = ly * lx;
    if (y0 < 0 || y0 >= HH) { w00 = 0.f; w01 = 0.f; }
    if (y1 < 0 || y1 >= HH) { w10 = 0.f; w11 = 0.f; }
    if (x0 < 0 || x0 >= WW) { w00 = 0.f; w10 = 0.f; }
    if (x1 < 0 || x1 >= WW) { w01 = 0.f; w11 = 0.f; }
    const int cy0 = min(max(y0, 0), HH - 1), cy1 = min(max(y1, 0), HH - 1);
    const int cx0 = min(max(x0, 0), WW - 1), cx1 = min(max(x1, 0), WW - 1);
    const int ty0 = cy0 - oy, ty1 = cy1 - oy;
    const int tx0 = cx0 - ox, tx1 = cx1 - ox;
    const bool intile = (ty0 >= 0) & (ty1 < TH) & (tx0 >= 0) & (tx1 < TWP);
    if (__builtin_amdgcn_ballot_w64(intile) == ~0ull) {
      t0[k] = ((ty0 * TWP + tx0) << 6) + (((quad + tx0) & 7) << 3);
      t1[k] = ((ty0 * TWP + tx1) << 6) + (((quad + tx1) & 7) << 3);
      t2[k] = ((ty1 * TWP + tx0) << 6) + (((quad + tx0) & 7) << 3);
      t3[k] = ((ty1 * TWP + tx1) << 6) + (((quad + tx1) & 7) << 3);
      lmask |= 1u << k;
    } else {
      t0[k] = ((cy0 * WW + cx0) << 6) + c0g;
      t1[k] = ((cy0 * WW + cx1) << 6) + c0g;
      t2[k] = ((cy1 * WW + cx0) << 6) + c0g;
      t3[k] = ((cy1 * WW + cx1) << 6) + c0g;
    }
    w0_[k] = w00; w1_[k] = w01; w2_[k] = w10; w3_[k] = w11;
  }
  lmask = __builtin_amdgcn_readfirstlane(lmask);

  f32x4 acc[4];
#pragma unroll
  for (int ot = 0; ot < 4; ot++)
#pragma unroll
    for (int r = 0; r < 4; r++) acc[ot][r] = 0.f;

  const bf16x8* wp = (const bf16x8*)wtd + l;

  __syncthreads();  // tile staged (precompute overlapped the drain)

#pragma unroll
  for (int k = 0; k < 9; k++) {
    bf16x8 v00a, v00b, v01a, v01b, v10a, v10b, v11a, v11b;
    if (lmask & (1u << k)) {
      v00a = *(const bf16x8*)&tile[t0[k]];
      v00b = *(const bf16x8*)&tile[t0[k] ^ 32];
      v01a = *(const bf16x8*)&tile[t1[k]];
      v01b = *(const bf16x8*)&tile[t1[k] ^ 32];
      v10a = *(const bf16x8*)&tile[t2[k]];
      v10b = *(const bf16x8*)&tile[t2[k] ^ 32];
      v11a = *(const bf16x8*)&tile[t3[k]];
      v11b = *(const bf16x8*)&tile[t3[k] ^ 32];
    } else {
      v00a = *(const bf16x8*)(xb + t0[k]);
      v00b = *(const bf16x8*)(xb + (t0[k] ^ 32));
      v01a = *(const bf16x8*)(xb + t1[k]);
      v01b = *(const bf16x8*)(xb + (t1[k] ^ 32));
      v10a = *(const bf16x8*)(xb + t2[k]);
      v10b = *(const bf16x8*)(xb + (t2[k] ^ 32));
      v11a = *(const bf16x8*)(xb + t3[k]);
      v11b = *(const bf16x8*)(xb + (t3[k] ^ 32));
    }

    bf16x8 bs0, bs1;
#pragma unroll
    for (int j = 0; j < 8; j++) {
      float sa = bf2f(v00a[j]) * w0_[k] + bf2f(v01a[j]) * w1_[k] +
                 bf2f(v10a[j]) * w2_[k] + bf2f(v11a[j]) * w3_[k];
      bs0[j] = f2bf(sa);
      float sb = bf2f(v00b[j]) * w0_[k] + bf2f(v01b[j]) * w1_[k] +
                 bf2f(v10b[j]) * w2_[k] + bf2f(v11b[j]) * w3_[k];
      bs1[j] = f2bf(sb);
    }

    acc[0] = __builtin_amdgcn_mfma_f32_16x16x32_bf16(wp[(k * 8 + 0) * 64], bs0, acc[0], 0, 0, 0);
    acc[1] = __builtin_amdgcn_mfma_f32_16x16x32_bf16(wp[(k * 8 + 1) * 64], bs0, acc[1], 0, 0, 0);
    acc[2] = __builtin_amdgcn_mfma_f32_16x16x32_bf16(wp[(k * 8 + 2) * 64], bs0, acc[2], 0, 0, 0);
    acc[3] = __builtin_amdgcn_mfma_f32_16x16x32_bf16(wp[(k * 8 + 3) * 64], bs0, acc[3], 0, 0, 0);
    acc[0] = __builtin_amdgcn_mfma_f32_16x16x32_bf16(wp[(k * 8 + 4) * 64], bs1, acc[0], 0, 0, 0);
    acc[1] = __builtin_amdgcn_mfma_f32_16x16x32_bf16(wp[(k * 8 + 5) * 64], bs1, acc[1], 0, 0, 0);
    acc[2] = __builtin_amdgcn_mfma_f32_16x16x32_bf16(wp[(k * 8 + 6) * 64], bs1, acc[2], 0, 0, 0);
    acc[3] = __builtin_amdgcn_mfma_f32_16x16x32_bf16(wp[(k * 8 + 7) * 64], bs1, acc[3], 0, 0, 0);
  }

#pragma unroll
  for (int ot = 0; ot < 4; ot++)
#pragma unroll
    for (int r = 0; r < 4; r++)
      acc[ot][r] += bias[ot * 16 + quad * 4 + r];

  if (outb) {
#pragma unroll
    for (int ot = 0; ot < 4; ot++) {
      short4 sv;
      sv.x = f2bf(acc[ot][0]); sv.y = f2bf(acc[ot][1]);
      sv.z = f2bf(acc[ot][2]); sv.w = f2bf(acc[ot][3]);
      *(short4*)(outb + (size_t)pix * 64 + ot * 16 + quad * 4) = sv;
    }
  }
  if (outf) {
    const int hw = pix & (HW - 1);
#pragma unroll
    for (int ot = 0; ot < 4; ot++)
#pragma unroll
      for (int r = 0; r < 4; r++) {
        const int o = ot * 16 + quad * 4 + r;
        outf[(size_t)b * (CC * HW) + (size_t)o * HW + hw] = acc[ot][r];
      }
  }
}

extern "C" void kernel_launch(void* const* d_in, const int* in_sizes, int n_in,
                              void* d_out, int out_size, void* d_ws, size_t ws_size,
                              hipStream_t stream) {
  const float* ref    = (const float*)d_in[0];
  const float* nbr    = (const float*)d_in[1];
  const float* w_off1 = (const float*)d_in[2];
  const float* b_off1 = (const float*)d_in[3];
  const float* w_d1   = (const float*)d_in[4];
  const float* b_d1   = (const float*)d_in[5];
  const float* w_off2 = (const float*)d_in[6];
  const float* b_off2 = (const float*)d_in[7];
  const float* w_d2   = (const float*)d_in[8];
  const float* b_d2   = (const float*)d_in[9];
  const float* w_off3 = (const float*)d_in[10];
  const float* b_off3 = (const float*)d_in[11];
  const float* w_d3   = (const float*)d_in[12];
  const float* b_d3   = (const float*)d_in[13];

  float* out = (float*)d_out;
  char* ws = (char*)d_ws;
  float* off_buf = (float*)(ws);               // planar 18*65536*4 = 4,718,592 B
  short* ref_bf  = (short*)(ws + 5242880);     // 8,388,608 B each
  short* nbr_bf  = (short*)(ws + 13631488);
  short* d1_bf   = (short*)(ws + 22020096);
  short* d2_bf   = (short*)(ws + 30408704);
  short* wtd1    = (short*)(ws + 38797312);    // 73,728 B each
  short* wtd2    = (short*)(ws + 38871040);
  short* wtd3    = (short*)(ws + 38944768);
  short* wtoff1  = (short*)(ws + 39018496);
  short* wtoff2  = (short*)(ws + 39092224);
  short* wtoff3  = (short*)(ws + 39165952);

  cast_nhwc_kernel<<<1024, 256, 0, stream>>>(ref, nbr, ref_bf, nbr_bf);
  prep_weights_all<<<432, 256, 0, stream>>>(
      w_d1, w_off1, wtd1, wtoff1,
      w_d2, w_off2, wtd2, wtoff2,
      w_d3, w_off3, wtd3, wtoff3);

  const int nblk_oc = BB * HW / 64;   // 1024 tiles of 4x16 px
  const int nblk_df = BB * HW / 128;  // 512 tiles of 8x16 px

  off_tile_kernel<<<nblk_oc, 256, 0, stream>>>(ref_bf, nbr_bf, wtoff1, b_off1, off_buf);
  deform_tile_kernel<<<nblk_df, 512, 0, stream>>>(nbr_bf, off_buf, wtd1, b_d1, nullptr, d1_bf);
  off_tile_kernel<<<nblk_oc, 256, 0, stream>>>(ref_bf, d1_bf, wtoff2, b_off2, off_buf);
  deform_tile_kernel<<<nblk_df, 512, 0, stream>>>(d1_bf, off_buf, wtd2, b_d2, nullptr, d2_bf);
  off_tile_kernel<<<nblk_oc, 256, 0, stream>>>(ref_bf, d2_bf, wtoff3, b_off3, off_buf);
  deform_tile_kernel<<<nblk_df, 512, 0, stream>>>(d2_bf, off_buf, wtd3, b_d3, out, nullptr);
}

// Round 17
// 124.134 us; speedup vs baseline: 1.1817x; 1.1817x over previous
//
#include <hip/hip_runtime.h>
#include <hip/hip_bf16.h>

#define BB 4
#define CC 64
#define HH 128
#define WW 128
#define HW (HH * WW)
#define TOTPIX (BB * HW)  // 65536

typedef short bf16x8 __attribute__((ext_vector_type(8)));
typedef float f32x4 __attribute__((ext_vector_type(4)));

static __device__ __forceinline__ short f2bf(float f) {
  __hip_bfloat16 h = __float2bfloat16(f);
  return __builtin_bit_cast(short, h);
}
static __device__ __forceinline__ float bf2f(short s) {
  unsigned int u = ((unsigned int)(unsigned short)s) << 16;
  return __builtin_bit_cast(float, u);
}

// async 16B/lane global -> LDS (wave-uniform LDS base + lane*16)
static __device__ __forceinline__ void stage1k(const short* g, short* lds) {
  __builtin_amdgcn_global_load_lds(
      (const __attribute__((address_space(1))) unsigned int*)g,
      (__attribute__((address_space(3))) unsigned int*)lds, 16, 0, 0);
}

// NCHW f32 -> NHWC bf16 for two tensors. Block = 64 px x 64 c tile.
__global__ __launch_bounds__(256) void cast_nhwc_kernel(
    const float* __restrict__ a, const float* __restrict__ b,
    short* __restrict__ oa, short* __restrict__ ob) {
  __shared__ float tile[64][68];
  const int bid = blockIdx.x;        // 1024 blocks
  const int bb = bid >> 8;           // batch
  const int hw0 = (bid & 255) * 64;  // 64-px stripe
  const int t = threadIdx.x;
  for (int s = 0; s < 2; s++) {
    const float* src = s ? b : a;
    short* dst = s ? ob : oa;
    if (s) __syncthreads();
    {
      const int lp = t & 15;  // 16 lanes x float4 = 64 px
      for (int c = (t >> 4); c < 64; c += 16) {
        float4 v = *(const float4*)&src[((size_t)(bb * 64 + c)) * HW + hw0 + lp * 4];
        *(float4*)&tile[c][lp * 4] = v;
      }
    }
    __syncthreads();
    {
      const int px = t >> 2;
      const int seg = t & 3;
      bf16x8 s0, s1;
#pragma unroll
      for (int i = 0; i < 8; i++) s0[i] = f2bf(tile[seg * 16 + i][px]);
#pragma unroll
      for (int i = 0; i < 8; i++) s1[i] = f2bf(tile[seg * 16 + 8 + i][px]);
      short* dp = dst + ((size_t)(bid * 64 + px)) * 64 + seg * 16;
      *(bf16x8*)dp = s0;
      *(bf16x8*)(dp + 8) = s1;
    }
  }
}

// Weight prep, all 3 stages in one launch (stage = blockIdx.x/144).
__global__ __launch_bounds__(256) void prep_weights_all(
    const float* __restrict__ wd1, const float* __restrict__ wo1,
    short* __restrict__ wtd1, short* __restrict__ wtoff1,
    const float* __restrict__ wd2, const float* __restrict__ wo2,
    short* __restrict__ wtd2, short* __restrict__ wtoff2,
    const float* __restrict__ wd3, const float* __restrict__ wo3,
    short* __restrict__ wtd3, short* __restrict__ wtoff3) {
  const int s = blockIdx.x / 144;
  const float* wd = (s == 0) ? wd1 : (s == 1) ? wd2 : wd3;
  const float* wo = (s == 0) ? wo1 : (s == 1) ? wo2 : wo3;
  short* wtd = (s == 0) ? wtd1 : (s == 1) ? wtd2 : wtd3;
  short* wtoff = (s == 0) ? wtoff1 : (s == 1) ? wtoff2 : wtoff3;
  const int i = (blockIdx.x % 144) * 256 + threadIdx.x;  // 0..36863
  const int j = i & 7, l = (i >> 3) & 63, f = i >> 9;
  {
    int ot = f & 3, cf = (f >> 2) & 1, k = f >> 3;
    int o = ot * 16 + (l & 15), c = cf * 32 + (l >> 4) * 8 + j;
    wtd[i] = f2bf(wd[(o * 64 + c) * 9 + k]);
  }
  {
    int ot = f & 1, ks = f >> 1;
    int cs = ks & 3, k = ks >> 2;
    int o = ot * 16 + (l & 15), c = cs * 32 + (l >> 4) * 8 + j;
    wtoff[i] = (o < 18) ? f2bf(wo[(o * 128 + c) * 9 + k]) : (short)0;
  }
}

// ---------- LDS-tiled MFMA offset conv (r14 + setprio) ----------
__global__ __launch_bounds__(256, 4) void off_tile_kernel(
    const short* __restrict__ ref, const short* __restrict__ x2,
    const short* __restrict__ wtoff, const float* __restrict__ bias,
    float* __restrict__ out) {
  __shared__ short tile[2 * 6 * 24 * 64];  // [tensor][row][px][64ch]
  int bid = blockIdx.x;
  bid = (bid & 7) * (gridDim.x >> 3) + (bid >> 3);  // 1024 % 8 == 0
  const int tid = threadIdx.x;
  const int l = tid & 63;
  const int g = __builtin_amdgcn_readfirstlane(tid >> 6);  // row-group 0..3
  const int col = l & 15, quad = l >> 4;
  const int b = bid >> 8;
  const int rem = bid & 255;
  const int h0 = (rem >> 3) * 4;   // 32 row-tiles
  const int w0 = (rem & 7) * 16;   // 8 col-tiles
  const int oy = h0 - 1, ox = w0 - 1;
  const int h = h0 + g, w = w0 + col;
  const int pix = ((b << 7) + h) * WW + w;

  const short* srcs[2] = {ref + (size_t)b * (HW * 64), x2 + (size_t)b * (HW * 64)};

  {
    const int tc = l >> 3;  // px-in-chunk 0..7
    const int m = l & 7;    // dest slot
#pragma unroll
    for (int i = 0; i < 9; i++) {
      const int idx = g + i * 4;        // 0..35, wave-uniform
      const int t = idx / 18;
      const int rr = (idx % 18) / 3, seg = idx % 3;
      const int iy = min(max(oy + rr, 0), HH - 1);
      const int tcol = seg * 8 + tc;
      const int ix = min(max(ox + tcol, 0), WW - 1);
      const int sc = (m - tcol) & 7;
      stage1k(srcs[t] + (((iy << 7) + ix) << 6) + sc * 8,
              &tile[((t * 6 + rr) * 24 + seg * 8) << 6]);
    }
  }

  f32x4 acc0 = {0.f, 0.f, 0.f, 0.f}, acc1 = {0.f, 0.f, 0.f, 0.f};
  const bf16x8* wp = (const bf16x8*)wtoff + l;

  __syncthreads();  // tile staged

#pragma unroll
  for (int k = 0; k < 9; k++) {
    const int ky = k / 3, kx = k - ky * 3;
    const int hh = h + ky - 1, ww2 = w + kx - 1;
    const bool valid = (hh >= 0) & (hh < HH) & (ww2 >= 0) & (ww2 < WW);
    const int tr = g + ky;      // 0..5
    const int tcx = col + kx;   // 0..17
    bf16x8 vv[4];
#pragma unroll
    for (int cs = 0; cs < 4; cs++) {
      const int t = cs >> 1;
      const int chunk = (cs & 1) * 4 + quad;  // 0..7 within pixel
      bf16x8 v = *(const bf16x8*)&tile[(((t * 6 + tr) * 24 + tcx) << 6) +
                                       (((chunk + tcx) & 7) << 3)];
      if (!valid) v = (bf16x8)(short)0;
      vv[cs] = v;
    }
    __builtin_amdgcn_s_setprio(1);
#pragma unroll
    for (int cs = 0; cs < 4; cs++) {
      const int f = (k * 4 + cs) * 2;
      acc0 = __builtin_amdgcn_mfma_f32_16x16x32_bf16(wp[f * 64], vv[cs], acc0, 0, 0, 0);
      acc1 = __builtin_amdgcn_mfma_f32_16x16x32_bf16(wp[(f + 1) * 64], vv[cs], acc1, 0, 0, 0);
    }
    __builtin_amdgcn_s_setprio(0);
  }

  // planar output: out[o][pix], coalesced 64B stores
#pragma unroll
  for (int r = 0; r < 4; r++)
    out[(quad * 4 + r) * TOTPIX + pix] = acc0[r] + bias[quad * 4 + r];
  if (quad == 0) {
    out[16 * TOTPIX + pix] = acc1[0] + bias[16];
    out[17 * TOTPIX + pix] = acc1[1] + bias[17];
  }
}

// ---------- LDS-tiled MFMA deformable conv (r14 + setprio, VGPR cap 85) ----------
// Block = 512 thr = 8 row-waves; output tile 8x16 px; halo 16x24 px
// (49KB, chunk-swizzled). Offsets read PLANAR (coalesced dword loads).
// launch_bounds(512,3): occupancy unchanged (grid=2/CU, LDS=3/CU), VGPR
// headroom 64->85 for voluntary pipelining. No sched_barrier (r15/r16 lesson).
#define TH 16
#define TWP 24
__global__ __launch_bounds__(512, 3) void deform_tile_kernel(
    const short* __restrict__ x, const float* __restrict__ off,
    const short* __restrict__ wtd, const float* __restrict__ bias,
    float* __restrict__ outf, short* __restrict__ outb) {
  __shared__ short tile[TH * TWP * 64];  // 49152 B
  int bid = blockIdx.x;
  bid = (bid & 7) * (gridDim.x >> 3) + (bid >> 3);  // 512 % 8 == 0
  const int tid = threadIdx.x;
  const int l = tid & 63;
  const int wv = __builtin_amdgcn_readfirstlane(tid >> 6);  // 0..7
  const int col = l & 15, quad = l >> 4;
  const int b = bid >> 7;
  const int rem = bid & 127;
  const int h0 = (rem >> 3) * 8;   // 16 row-tiles
  const int w0 = (rem & 7) * 16;   // 8 col-tiles
  const int oy = h0 - 4, ox = w0 - 4;
  const int h = h0 + wv, w = w0 + col;
  const int pix = ((b << 7) + h) * WW + w;

  const short* xb = x + (size_t)b * (HW * 64);

  // ---- stage 16x24-px halo tile, chunk-swizzled source ----
  {
    const int tc = ((l >> 3) & 7);
    const int m = l & 7;
#pragma unroll
    for (int i = 0; i < 6; i++) {
      const int idx = wv + i * 8;        // 0..47
      const int r = idx / 3, seg = idx % 3;
      const int iy = min(max(oy + r, 0), HH - 1);
      const int tcol = seg * 8 + tc;
      const int ix = min(max(ox + tcol, 0), WW - 1);
      const int sc = (m - tcol) & 7;
      stage1k(xb + (((iy << 7) + ix) << 6) + sc * 8,
              &tile[((r * TWP + seg * 8) << 6)]);
    }
  }

  // planar offsets: off[j][pix], 18 coalesced dword loads
  float offv[18];
#pragma unroll
  for (int j = 0; j < 18; j++) offv[j] = off[j * TOTPIX + pix];

  f32x4 acc[4];
#pragma unroll
  for (int ot = 0; ot < 4; ot++)
#pragma unroll
    for (int r = 0; r < 4; r++) acc[ot][r] = 0.f;

  const int c0g = quad * 8;
  const bf16x8* wp = (const bf16x8*)wtd + l;

  __syncthreads();  // tile staged

#pragma unroll
  for (int k = 0; k < 9; k++) {
    const int ky = k / 3, kx = k - ky * 3;
    const float py = (float)(h - 1 + ky) + offv[2 * k];
    const float pxx = (float)(w - 1 + kx) + offv[2 * k + 1];
    const float y0f = floorf(py), x0f = floorf(pxx);
    const float ly = py - y0f, lx = pxx - x0f;
    const int y0 = (int)y0f, x0 = (int)x0f;
    const int y1 = y0 + 1, x1 = x0 + 1;
    float w00 = (1.f - ly) * (1.f - lx), w01 = (1.f - ly) * lx;
    float w10 = ly * (1.f - lx), w11 = ly * lx;
    if (y0 < 0 || y0 >= HH) { w00 = 0.f; w01 = 0.f; }
    if (y1 < 0 || y1 >= HH) { w10 = 0.f; w11 = 0.f; }
    if (x0 < 0 || x0 >= WW) { w00 = 0.f; w10 = 0.f; }
    if (x1 < 0 || x1 >= WW) { w01 = 0.f; w11 = 0.f; }
    const int cy0 = min(max(y0, 0), HH - 1), cy1 = min(max(y1, 0), HH - 1);
    const int cx0 = min(max(x0, 0), WW - 1), cx1 = min(max(x1, 0), WW - 1);

    const int ty0 = cy0 - oy, ty1 = cy1 - oy;
    const int tx0 = cx0 - ox, tx1 = cx1 - ox;
    const bool intile = (ty0 >= 0) & (ty1 < TH) & (tx0 >= 0) & (tx1 < TWP);

    bf16x8 v00a, v00b, v01a, v01b, v10a, v10b, v11a, v11b;
    if (__builtin_amdgcn_ballot_w64(intile) == ~0ull) {
      const int p00 = ((ty0 * TWP + tx0) << 6);
      const int p01 = ((ty0 * TWP + tx1) << 6);
      const int p10 = ((ty1 * TWP + tx0) << 6);
      const int p11 = ((ty1 * TWP + tx1) << 6);
      v00a = *(const bf16x8*)&tile[p00 + (((quad + tx0) & 7) << 3)];
      v00b = *(const bf16x8*)&tile[p00 + (((quad + 4 + tx0) & 7) << 3)];
      v01a = *(const bf16x8*)&tile[p01 + (((quad + tx1) & 7) << 3)];
      v01b = *(const bf16x8*)&tile[p01 + (((quad + 4 + tx1) & 7) << 3)];
      v10a = *(const bf16x8*)&tile[p10 + (((quad + tx0) & 7) << 3)];
      v10b = *(const bf16x8*)&tile[p10 + (((quad + 4 + tx0) & 7) << 3)];
      v11a = *(const bf16x8*)&tile[p11 + (((quad + tx1) & 7) << 3)];
      v11b = *(const bf16x8*)&tile[p11 + (((quad + 4 + tx1) & 7) << 3)];
    } else {
      const int p00 = ((cy0 * WW + cx0) << 6) + c0g;
      const int p01 = ((cy0 * WW + cx1) << 6) + c0g;
      const int p10 = ((cy1 * WW + cx0) << 6) + c0g;
      const int p11 = ((cy1 * WW + cx1) << 6) + c0g;
      v00a = *(const bf16x8*)(xb + p00);
      v00b = *(const bf16x8*)(xb + p00 + 32);
      v01a = *(const bf16x8*)(xb + p01);
      v01b = *(const bf16x8*)(xb + p01 + 32);
      v10a = *(const bf16x8*)(xb + p10);
      v10b = *(const bf16x8*)(xb + p10 + 32);
      v11a = *(const bf16x8*)(xb + p11);
      v11b = *(const bf16x8*)(xb + p11 + 32);
    }

    bf16x8 bs0, bs1;
#pragma unroll
    for (int j = 0; j < 8; j++) {
      float sa = bf2f(v00a[j]) * w00 + bf2f(v01a[j]) * w01 +
                 bf2f(v10a[j]) * w10 + bf2f(v11a[j]) * w11;
      bs0[j] = f2bf(sa);
      float sb = bf2f(v00b[j]) * w00 + bf2f(v01b[j]) * w01 +
                 bf2f(v10b[j]) * w10 + bf2f(v11b[j]) * w11;
      bs1[j] = f2bf(sb);
    }

    __builtin_amdgcn_s_setprio(1);
    acc[0] = __builtin_amdgcn_mfma_f32_16x16x32_bf16(wp[(k * 8 + 0) * 64], bs0, acc[0], 0, 0, 0);
    acc[1] = __builtin_amdgcn_mfma_f32_16x16x32_bf16(wp[(k * 8 + 1) * 64], bs0, acc[1], 0, 0, 0);
    acc[2] = __builtin_amdgcn_mfma_f32_16x16x32_bf16(wp[(k * 8 + 2) * 64], bs0, acc[2], 0, 0, 0);
    acc[3] = __builtin_amdgcn_mfma_f32_16x16x32_bf16(wp[(k * 8 + 3) * 64], bs0, acc[3], 0, 0, 0);
    acc[0] = __builtin_amdgcn_mfma_f32_16x16x32_bf16(wp[(k * 8 + 4) * 64], bs1, acc[0], 0, 0, 0);
    acc[1] = __builtin_amdgcn_mfma_f32_16x16x32_bf16(wp[(k * 8 + 5) * 64], bs1, acc[1], 0, 0, 0);
    acc[2] = __builtin_amdgcn_mfma_f32_16x16x32_bf16(wp[(k * 8 + 6) * 64], bs1, acc[2], 0, 0, 0);
    acc[3] = __builtin_amdgcn_mfma_f32_16x16x32_bf16(wp[(k * 8 + 7) * 64], bs1, acc[3], 0, 0, 0);
    __builtin_amdgcn_s_setprio(0);
  }

#pragma unroll
  for (int ot = 0; ot < 4; ot++)
#pragma unroll
    for (int r = 0; r < 4; r++)
      acc[ot][r] += bias[ot * 16 + quad * 4 + r];

  if (outb) {
#pragma unroll
    for (int ot = 0; ot < 4; ot++) {
      short4 sv;
      sv.x = f2bf(acc[ot][0]); sv.y = f2bf(acc[ot][1]);
      sv.z = f2bf(acc[ot][2]); sv.w = f2bf(acc[ot][3]);
      *(short4*)(outb + (size_t)pix * 64 + ot * 16 + quad * 4) = sv;
    }
  }
  if (outf) {
    const int hw = pix & (HW - 1);
#pragma unroll
    for (int ot = 0; ot < 4; ot++)
#pragma unroll
      for (int r = 0; r < 4; r++) {
        const int o = ot * 16 + quad * 4 + r;
        outf[(size_t)b * (CC * HW) + (size_t)o * HW + hw] = acc[ot][r];
      }
  }
}

extern "C" void kernel_launch(void* const* d_in, const int* in_sizes, int n_in,
                              void* d_out, int out_size, void* d_ws, size_t ws_size,
                              hipStream_t stream) {
  const float* ref    = (const float*)d_in[0];
  const float* nbr    = (const float*)d_in[1];
  const float* w_off1 = (const float*)d_in[2];
  const float* b_off1 = (const float*)d_in[3];
  const float* w_d1   = (const float*)d_in[4];
  const float* b_d1   = (const float*)d_in[5];
  const float* w_off2 = (const float*)d_in[6];
  const float* b_off2 = (const float*)d_in[7];
  const float* w_d2   = (const float*)d_in[8];
  const float* b_d2   = (const float*)d_in[9];
  const float* w_off3 = (const float*)d_in[10];
  const float* b_off3 = (const float*)d_in[11];
  const float* w_d3   = (const float*)d_in[12];
  const float* b_d3   = (const float*)d_in[13];

  float* out = (float*)d_out;
  char* ws = (char*)d_ws;
  float* off_buf = (float*)(ws);               // planar 18*65536*4 = 4,718,592 B
  short* ref_bf  = (short*)(ws + 5242880);     // 8,388,608 B each
  short* nbr_bf  = (short*)(ws + 13631488);
  short* d1_bf   = (short*)(ws + 22020096);
  short* d2_bf   = (short*)(ws + 30408704);
  short* wtd1    = (short*)(ws + 38797312);    // 73,728 B each
  short* wtd2    = (short*)(ws + 38871040);
  short* wtd3    = (short*)(ws + 38944768);
  short* wtoff1  = (short*)(ws + 39018496);
  short* wtoff2  = (short*)(ws + 39092224);
  short* wtoff3  = (short*)(ws + 39165952);

  cast_nhwc_kernel<<<1024, 256, 0, stream>>>(ref, nbr, ref_bf, nbr_bf);
  prep_weights_all<<<432, 256, 0, stream>>>(
      w_d1, w_off1, wtd1, wtoff1,
      w_d2, w_off2, wtd2, wtoff2,
      w_d3, w_off3, wtd3, wtoff3);

  const int nblk_oc = BB * HW / 64;   // 1024 tiles of 4x16 px
  const int nblk_df = BB * HW / 128;  // 512 tiles of 8x16 px

  off_tile_kernel<<<nblk_oc, 256, 0, stream>>>(ref_bf, nbr_bf, wtoff1, b_off1, off_buf);
  deform_tile_kernel<<<nblk_df, 512, 0, stream>>>(nbr_bf, off_buf, wtd1, b_d1, nullptr, d1_bf);
  off_tile_kernel<<<nblk_oc, 256, 0, stream>>>(ref_bf, d1_bf, wtoff2, b_off2, off_buf);
  deform_tile_kernel<<<nblk_df, 512, 0, stream>>>(d1_bf, off_buf, wtd2, b_d2, nullptr, d2_bf);
  off_tile_kernel<<<nblk_oc, 256, 0, stream>>>(ref_bf, d2_bf, wtoff3, b_off3, off_buf);
  deform_tile_kernel<<<nblk_df, 512, 0, stream>>>(d2_bf, off_buf, wtd3, b_d3, out, nullptr);
}

// Round 18
// 122.371 us; speedup vs baseline: 1.1987x; 1.0144x over previous
//
#include <hip/hip_runtime.h>
#include <hip/hip_bf16.h>

#define BB 4
#define CC 64
#define HH 128
#define WW 128
#define HW (HH * WW)
#define TOTPIX (BB * HW)  // 65536

typedef short bf16x8 __attribute__((ext_vector_type(8)));
typedef float f32x4 __attribute__((ext_vector_type(4)));

static __device__ __forceinline__ short f2bf(float f) {
  __hip_bfloat16 h = __float2bfloat16(f);
  return __builtin_bit_cast(short, h);
}
static __device__ __forceinline__ float bf2f(short s) {
  unsigned int u = ((unsigned int)(unsigned short)s) << 16;
  return __builtin_bit_cast(float, u);
}

// async 16B/lane global -> LDS (wave-uniform LDS base + lane*16)
static __device__ __forceinline__ void stage1k(const short* g, short* lds) {
  __builtin_amdgcn_global_load_lds(
      (const __attribute__((address_space(1))) unsigned int*)g,
      (__attribute__((address_space(3))) unsigned int*)lds, 16, 0, 0);
}

// NCHW f32 -> NHWC bf16 for two tensors. Block = 64 px x 64 c tile.
__global__ __launch_bounds__(256) void cast_nhwc_kernel(
    const float* __restrict__ a, const float* __restrict__ b,
    short* __restrict__ oa, short* __restrict__ ob) {
  __shared__ float tile[64][68];
  const int bid = blockIdx.x;        // 1024 blocks
  const int bb = bid >> 8;           // batch
  const int hw0 = (bid & 255) * 64;  // 64-px stripe
  const int t = threadIdx.x;
  for (int s = 0; s < 2; s++) {
    const float* src = s ? b : a;
    short* dst = s ? ob : oa;
    if (s) __syncthreads();
    {
      const int lp = t & 15;  // 16 lanes x float4 = 64 px
      for (int c = (t >> 4); c < 64; c += 16) {
        float4 v = *(const float4*)&src[((size_t)(bb * 64 + c)) * HW + hw0 + lp * 4];
        *(float4*)&tile[c][lp * 4] = v;
      }
    }
    __syncthreads();
    {
      const int px = t >> 2;
      const int seg = t & 3;
      bf16x8 s0, s1;
#pragma unroll
      for (int i = 0; i < 8; i++) s0[i] = f2bf(tile[seg * 16 + i][px]);
#pragma unroll
      for (int i = 0; i < 8; i++) s1[i] = f2bf(tile[seg * 16 + 8 + i][px]);
      short* dp = dst + ((size_t)(bid * 64 + px)) * 64 + seg * 16;
      *(bf16x8*)dp = s0;
      *(bf16x8*)(dp + 8) = s1;
    }
  }
}

// Weight prep, all 3 stages in one launch (stage = blockIdx.x/144).
__global__ __launch_bounds__(256) void prep_weights_all(
    const float* __restrict__ wd1, const float* __restrict__ wo1,
    short* __restrict__ wtd1, short* __restrict__ wtoff1,
    const float* __restrict__ wd2, const float* __restrict__ wo2,
    short* __restrict__ wtd2, short* __restrict__ wtoff2,
    const float* __restrict__ wd3, const float* __restrict__ wo3,
    short* __restrict__ wtd3, short* __restrict__ wtoff3) {
  const int s = blockIdx.x / 144;
  const float* wd = (s == 0) ? wd1 : (s == 1) ? wd2 : wd3;
  const float* wo = (s == 0) ? wo1 : (s == 1) ? wo2 : wo3;
  short* wtd = (s == 0) ? wtd1 : (s == 1) ? wtd2 : wtd3;
  short* wtoff = (s == 0) ? wtoff1 : (s == 1) ? wtoff2 : wtoff3;
  const int i = (blockIdx.x % 144) * 256 + threadIdx.x;  // 0..36863
  const int j = i & 7, l = (i >> 3) & 63, f = i >> 9;
  {
    int ot = f & 3, cf = (f >> 2) & 1, k = f >> 3;
    int o = ot * 16 + (l & 15), c = cf * 32 + (l >> 4) * 8 + j;
    wtd[i] = f2bf(wd[(o * 64 + c) * 9 + k]);
  }
  {
    int ot = f & 1, ks = f >> 1;
    int cs = ks & 3, k = ks >> 2;
    int o = ot * 16 + (l & 15), c = cs * 32 + (l >> 4) * 8 + j;
    wtoff[i] = (o < 18) ? f2bf(wo[(o * 128 + c) * 9 + k]) : (short)0;
  }
}

// ---------- LDS-tiled MFMA offset conv (r14, unchanged) ----------
__global__ __launch_bounds__(256, 4) void off_tile_kernel(
    const short* __restrict__ ref, const short* __restrict__ x2,
    const short* __restrict__ wtoff, const float* __restrict__ bias,
    float* __restrict__ out) {
  __shared__ short tile[2 * 6 * 24 * 64];  // [tensor][row][px][64ch]
  int bid = blockIdx.x;
  bid = (bid & 7) * (gridDim.x >> 3) + (bid >> 3);  // 1024 % 8 == 0
  const int tid = threadIdx.x;
  const int l = tid & 63;
  const int g = __builtin_amdgcn_readfirstlane(tid >> 6);  // row-group 0..3
  const int col = l & 15, quad = l >> 4;
  const int b = bid >> 8;
  const int rem = bid & 255;
  const int h0 = (rem >> 3) * 4;   // 32 row-tiles
  const int w0 = (rem & 7) * 16;   // 8 col-tiles
  const int oy = h0 - 1, ox = w0 - 1;
  const int h = h0 + g, w = w0 + col;
  const int pix = ((b << 7) + h) * WW + w;

  const short* srcs[2] = {ref + (size_t)b * (HW * 64), x2 + (size_t)b * (HW * 64)};

  {
    const int tc = l >> 3;  // px-in-chunk 0..7
    const int m = l & 7;    // dest slot
#pragma unroll
    for (int i = 0; i < 9; i++) {
      const int idx = g + i * 4;        // 0..35, wave-uniform
      const int t = idx / 18;
      const int rr = (idx % 18) / 3, seg = idx % 3;
      const int iy = min(max(oy + rr, 0), HH - 1);
      const int tcol = seg * 8 + tc;
      const int ix = min(max(ox + tcol, 0), WW - 1);
      const int sc = (m - tcol) & 7;
      stage1k(srcs[t] + (((iy << 7) + ix) << 6) + sc * 8,
              &tile[((t * 6 + rr) * 24 + seg * 8) << 6]);
    }
  }

  f32x4 acc0 = {0.f, 0.f, 0.f, 0.f}, acc1 = {0.f, 0.f, 0.f, 0.f};
  const bf16x8* wp = (const bf16x8*)wtoff + l;

  __syncthreads();  // tile staged

#pragma unroll
  for (int k = 0; k < 9; k++) {
    const int ky = k / 3, kx = k - ky * 3;
    const int hh = h + ky - 1, ww2 = w + kx - 1;
    const bool valid = (hh >= 0) & (hh < HH) & (ww2 >= 0) & (ww2 < WW);
    const int tr = g + ky;      // 0..5
    const int tcx = col + kx;   // 0..17
#pragma unroll
    for (int cs = 0; cs < 4; cs++) {
      const int t = cs >> 1;
      const int chunk = (cs & 1) * 4 + quad;  // 0..7 within pixel
      bf16x8 v = *(const bf16x8*)&tile[(((t * 6 + tr) * 24 + tcx) << 6) +
                                       (((chunk + tcx) & 7) << 3)];
      if (!valid) v = (bf16x8)(short)0;
      const int f = (k * 4 + cs) * 2;
      acc0 = __builtin_amdgcn_mfma_f32_16x16x32_bf16(wp[f * 64], v, acc0, 0, 0, 0);
      acc1 = __builtin_amdgcn_mfma_f32_16x16x32_bf16(wp[(f + 1) * 64], v, acc1, 0, 0, 0);
    }
  }

  // planar output: out[o][pix], coalesced 64B stores
#pragma unroll
  for (int r = 0; r < 4; r++)
    out[(quad * 4 + r) * TOTPIX + pix] = acc0[r] + bias[quad * 4 + r];
  if (quad == 0) {
    out[16 * TOTPIX + pix] = acc1[0] + bias[16];
    out[17 * TOTPIX + pix] = acc1[1] + bias[17];
  }
}

// ---------- LDS-tiled MFMA deformable conv, branch-free hot path ----------
// Block = 512 thr = 8 row-waves; output tile 8x16 px; halo 16x24 px (49KB).
// Pre-pass computes per-wave lmask (all-lanes-in-tile per tap) BEFORE the
// staging barrier. If all 9 taps are in-tile (the ~always case), the k-loop
// is completely branch-free -> compiler can pipeline ds_reads across taps.
// Fallback loop (r14 per-tap branch) preserves correctness for any data.
#define TH 16
#define TWP 24

#define DEF_TAP_MATH(k)                                                     \
  const int ky = (k) / 3, kx = (k) - ky * 3;                                \
  const float py = (float)(h - 1 + ky) + offv[2 * (k)];                     \
  const float pxx = (float)(w - 1 + kx) + offv[2 * (k) + 1];                \
  const float y0f = floorf(py), x0f = floorf(pxx);                          \
  const float ly = py - y0f, lx = pxx - x0f;                                \
  const int y0 = (int)y0f, x0 = (int)x0f;                                   \
  const int y1 = y0 + 1, x1 = x0 + 1;                                       \
  float w00 = (1.f - ly) * (1.f - lx), w01 = (1.f - ly) * lx;               \
  float w10 = ly * (1.f - lx), w11 = ly * lx;                               \
  if (y0 < 0 || y0 >= HH) { w00 = 0.f; w01 = 0.f; }                         \
  if (y1 < 0 || y1 >= HH) { w10 = 0.f; w11 = 0.f; }                         \
  if (x0 < 0 || x0 >= WW) { w00 = 0.f; w10 = 0.f; }                         \
  if (x1 < 0 || x1 >= WW) { w01 = 0.f; w11 = 0.f; }                         \
  const int cy0 = min(max(y0, 0), HH - 1), cy1 = min(max(y1, 0), HH - 1);   \
  const int cx0 = min(max(x0, 0), WW - 1), cx1 = min(max(x1, 0), WW - 1);

#define DEF_TAP_BLEND_MFMA(k)                                               \
  bf16x8 bs0, bs1;                                                          \
  _Pragma("unroll") for (int j = 0; j < 8; j++) {                           \
    float sa = bf2f(v00a[j]) * w00 + bf2f(v01a[j]) * w01 +                  \
               bf2f(v10a[j]) * w10 + bf2f(v11a[j]) * w11;                   \
    bs0[j] = f2bf(sa);                                                      \
    float sb = bf2f(v00b[j]) * w00 + bf2f(v01b[j]) * w01 +                  \
               bf2f(v10b[j]) * w10 + bf2f(v11b[j]) * w11;                   \
    bs1[j] = f2bf(sb);                                                      \
  }                                                                         \
  acc[0] = __builtin_amdgcn_mfma_f32_16x16x32_bf16(wp[((k) * 8 + 0) * 64], bs0, acc[0], 0, 0, 0); \
  acc[1] = __builtin_amdgcn_mfma_f32_16x16x32_bf16(wp[((k) * 8 + 1) * 64], bs0, acc[1], 0, 0, 0); \
  acc[2] = __builtin_amdgcn_mfma_f32_16x16x32_bf16(wp[((k) * 8 + 2) * 64], bs0, acc[2], 0, 0, 0); \
  acc[3] = __builtin_amdgcn_mfma_f32_16x16x32_bf16(wp[((k) * 8 + 3) * 64], bs0, acc[3], 0, 0, 0); \
  acc[0] = __builtin_amdgcn_mfma_f32_16x16x32_bf16(wp[((k) * 8 + 4) * 64], bs1, acc[0], 0, 0, 0); \
  acc[1] = __builtin_amdgcn_mfma_f32_16x16x32_bf16(wp[((k) * 8 + 5) * 64], bs1, acc[1], 0, 0, 0); \
  acc[2] = __builtin_amdgcn_mfma_f32_16x16x32_bf16(wp[((k) * 8 + 6) * 64], bs1, acc[2], 0, 0, 0); \
  acc[3] = __builtin_amdgcn_mfma_f32_16x16x32_bf16(wp[((k) * 8 + 7) * 64], bs1, acc[3], 0, 0, 0);

__global__ __launch_bounds__(512, 3) void deform_tile_kernel(
    const short* __restrict__ x, const float* __restrict__ off,
    const short* __restrict__ wtd, const float* __restrict__ bias,
    float* __restrict__ outf, short* __restrict__ outb) {
  __shared__ short tile[TH * TWP * 64];  // 49152 B
  int bid = blockIdx.x;
  bid = (bid & 7) * (gridDim.x >> 3) + (bid >> 3);  // 512 % 8 == 0
  const int tid = threadIdx.x;
  const int l = tid & 63;
  const int wv = __builtin_amdgcn_readfirstlane(tid >> 6);  // 0..7
  const int col = l & 15, quad = l >> 4;
  const int b = bid >> 7;
  const int rem = bid & 127;
  const int h0 = (rem >> 3) * 8;   // 16 row-tiles
  const int w0 = (rem & 7) * 16;   // 8 col-tiles
  const int oy = h0 - 4, ox = w0 - 4;
  const int h = h0 + wv, w = w0 + col;
  const int pix = ((b << 7) + h) * WW + w;

  const short* xb = x + (size_t)b * (HW * 64);

  // ---- stage 16x24-px halo tile, chunk-swizzled source ----
  {
    const int tc = ((l >> 3) & 7);
    const int m = l & 7;
#pragma unroll
    for (int i = 0; i < 6; i++) {
      const int idx = wv + i * 8;        // 0..47
      const int r = idx / 3, seg = idx % 3;
      const int iy = min(max(oy + r, 0), HH - 1);
      const int tcol = seg * 8 + tc;
      const int ix = min(max(ox + tcol, 0), WW - 1);
      const int sc = (m - tcol) & 7;
      stage1k(xb + (((iy << 7) + ix) << 6) + sc * 8,
              &tile[((r * TWP + seg * 8) << 6)]);
    }
  }

  // planar offsets: off[j][pix], 18 coalesced dword loads
  float offv[18];
#pragma unroll
  for (int j = 0; j < 18; j++) offv[j] = off[j * TOTPIX + pix];

  // ---- pre-pass (overlaps staging drain): per-wave all-in-tile mask ----
  unsigned lmask = 0;
#pragma unroll
  for (int k = 0; k < 9; k++) {
    const int ky = k / 3, kx = k - ky * 3;
    const float py = (float)(h - 1 + ky) + offv[2 * k];
    const float pxx = (float)(w - 1 + kx) + offv[2 * k + 1];
    const int y0 = (int)floorf(py), x0 = (int)floorf(pxx);
    const int cy0 = min(max(y0, 0), HH - 1), cy1 = min(max(y0 + 1, 0), HH - 1);
    const int cx0 = min(max(x0, 0), WW - 1), cx1 = min(max(x0 + 1, 0), WW - 1);
    const bool intile = (cy0 - oy >= 0) & (cy1 - oy < TH) &
                        (cx0 - ox >= 0) & (cx1 - ox < TWP);
    if (__builtin_amdgcn_ballot_w64(intile) == ~0ull) lmask |= 1u << k;
  }
  lmask = __builtin_amdgcn_readfirstlane(lmask);

  f32x4 acc[4];
#pragma unroll
  for (int ot = 0; ot < 4; ot++)
#pragma unroll
    for (int r = 0; r < 4; r++) acc[ot][r] = 0.f;

  const int c0g = quad * 8;
  const bf16x8* wp = (const bf16x8*)wtd + l;

  __syncthreads();  // tile staged

  if (lmask == 0x1FFu) {
    // ================= branch-free hot path =================
#pragma unroll
    for (int k = 0; k < 9; k++) {
      DEF_TAP_MATH(k)
      const int ty0 = cy0 - oy, ty1 = cy1 - oy;
      const int tx0 = cx0 - ox, tx1 = cx1 - ox;
      const int p00 = ((ty0 * TWP + tx0) << 6);
      const int p01 = ((ty0 * TWP + tx1) << 6);
      const int p10 = ((ty1 * TWP + tx0) << 6);
      const int p11 = ((ty1 * TWP + tx1) << 6);
      bf16x8 v00a = *(const bf16x8*)&tile[p00 + (((quad + tx0) & 7) << 3)];
      bf16x8 v00b = *(const bf16x8*)&tile[p00 + (((quad + 4 + tx0) & 7) << 3)];
      bf16x8 v01a = *(const bf16x8*)&tile[p01 + (((quad + tx1) & 7) << 3)];
      bf16x8 v01b = *(const bf16x8*)&tile[p01 + (((quad + 4 + tx1) & 7) << 3)];
      bf16x8 v10a = *(const bf16x8*)&tile[p10 + (((quad + tx0) & 7) << 3)];
      bf16x8 v10b = *(const bf16x8*)&tile[p10 + (((quad + 4 + tx0) & 7) << 3)];
      bf16x8 v11a = *(const bf16x8*)&tile[p11 + (((quad + tx1) & 7) << 3)];
      bf16x8 v11b = *(const bf16x8*)&tile[p11 + (((quad + 4 + tx1) & 7) << 3)];
      DEF_TAP_BLEND_MFMA(k)
    }
  } else {
    // ================= mixed fallback (r14 body) =================
#pragma unroll
    for (int k = 0; k < 9; k++) {
      DEF_TAP_MATH(k)
      const int ty0 = cy0 - oy, ty1 = cy1 - oy;
      const int tx0 = cx0 - ox, tx1 = cx1 - ox;
      bf16x8 v00a, v00b, v01a, v01b, v10a, v10b, v11a, v11b;
      if (lmask & (1u << k)) {
        const int p00 = ((ty0 * TWP + tx0) << 6);
        const int p01 = ((ty0 * TWP + tx1) << 6);
        const int p10 = ((ty1 * TWP + tx0) << 6);
        const int p11 = ((ty1 * TWP + tx1) << 6);
        v00a = *(const bf16x8*)&tile[p00 + (((quad + tx0) & 7) << 3)];
        v00b = *(const bf16x8*)&tile[p00 + (((quad + 4 + tx0) & 7) << 3)];
        v01a = *(const bf16x8*)&tile[p01 + (((quad + tx1) & 7) << 3)];
        v01b = *(const bf16x8*)&tile[p01 + (((quad + 4 + tx1) & 7) << 3)];
        v10a = *(const bf16x8*)&tile[p10 + (((quad + tx0) & 7) << 3)];
        v10b = *(const bf16x8*)&tile[p10 + (((quad + 4 + tx0) & 7) << 3)];
        v11a = *(const bf16x8*)&tile[p11 + (((quad + tx1) & 7) << 3)];
        v11b = *(const bf16x8*)&tile[p11 + (((quad + 4 + tx1) & 7) << 3)];
      } else {
        const int p00 = ((cy0 * WW + cx0) << 6) + c0g;
        const int p01 = ((cy0 * WW + cx1) << 6) + c0g;
        const int p10 = ((cy1 * WW + cx0) << 6) + c0g;
        const int p11 = ((cy1 * WW + cx1) << 6) + c0g;
        v00a = *(const bf16x8*)(xb + p00);
        v00b = *(const bf16x8*)(xb + p00 + 32);
        v01a = *(const bf16x8*)(xb + p01);
        v01b = *(const bf16x8*)(xb + p01 + 32);
        v10a = *(const bf16x8*)(xb + p10);
        v10b = *(const bf16x8*)(xb + p10 + 32);
        v11a = *(const bf16x8*)(xb + p11);
        v11b = *(const bf16x8*)(xb + p11 + 32);
      }
      DEF_TAP_BLEND_MFMA(k)
    }
  }

#pragma unroll
  for (int ot = 0; ot < 4; ot++)
#pragma unroll
    for (int r = 0; r < 4; r++)
      acc[ot][r] += bias[ot * 16 + quad * 4 + r];

  if (outb) {
#pragma unroll
    for (int ot = 0; ot < 4; ot++) {
      short4 sv;
      sv.x = f2bf(acc[ot][0]); sv.y = f2bf(acc[ot][1]);
      sv.z = f2bf(acc[ot][2]); sv.w = f2bf(acc[ot][3]);
      *(short4*)(outb + (size_t)pix * 64 + ot * 16 + quad * 4) = sv;
    }
  }
  if (outf) {
    const int hw = pix & (HW - 1);
#pragma unroll
    for (int ot = 0; ot < 4; ot++)
#pragma unroll
      for (int r = 0; r < 4; r++) {
        const int o = ot * 16 + quad * 4 + r;
        outf[(size_t)b * (CC * HW) + (size_t)o * HW + hw] = acc[ot][r];
      }
  }
}

extern "C" void kernel_launch(void* const* d_in, const int* in_sizes, int n_in,
                              void* d_out, int out_size, void* d_ws, size_t ws_size,
                              hipStream_t stream) {
  const float* ref    = (const float*)d_in[0];
  const float* nbr    = (const float*)d_in[1];
  const float* w_off1 = (const float*)d_in[2];
  const float* b_off1 = (const float*)d_in[3];
  const float* w_d1   = (const float*)d_in[4];
  const float* b_d1   = (const float*)d_in[5];
  const float* w_off2 = (const float*)d_in[6];
  const float* b_off2 = (const float*)d_in[7];
  const float* w_d2   = (const float*)d_in[8];
  const float* b_d2   = (const float*)d_in[9];
  const float* w_off3 = (const float*)d_in[10];
  const float* b_off3 = (const float*)d_in[11];
  const float* w_d3   = (const float*)d_in[12];
  const float* b_d3   = (const float*)d_in[13];

  float* out = (float*)d_out;
  char* ws = (char*)d_ws;
  float* off_buf = (float*)(ws);               // planar 18*65536*4 = 4,718,592 B
  short* ref_bf  = (short*)(ws + 5242880);     // 8,388,608 B each
  short* nbr_bf  = (short*)(ws + 13631488);
  short* d1_bf   = (short*)(ws + 22020096);
  short* d2_bf   = (short*)(ws + 30408704);
  short* wtd1    = (short*)(ws + 38797312);    // 73,728 B each
  short* wtd2    = (short*)(ws + 38871040);
  short* wtd3    = (short*)(ws + 38944768);
  short* wtoff1  = (short*)(ws + 39018496);
  short* wtoff2  = (short*)(ws + 39092224);
  short* wtoff3  = (short*)(ws + 39165952);

  cast_nhwc_kernel<<<1024, 256, 0, stream>>>(ref, nbr, ref_bf, nbr_bf);
  prep_weights_all<<<432, 256, 0, stream>>>(
      w_d1, w_off1, wtd1, wtoff1,
      w_d2, w_off2, wtd2, wtoff2,
      w_d3, w_off3, wtd3, wtoff3);

  const int nblk_oc = BB * HW / 64;   // 1024 tiles of 4x16 px
  const int nblk_df = BB * HW / 128;  // 512 tiles of 8x16 px

  off_tile_kernel<<<nblk_oc, 256, 0, stream>>>(ref_bf, nbr_bf, wtoff1, b_off1, off_buf);
  deform_tile_kernel<<<nblk_df, 512, 0, stream>>>(nbr_bf, off_buf, wtd1, b_d1, nullptr, d1_bf);
  off_tile_kernel<<<nblk_oc, 256, 0, stream>>>(ref_bf, d1_bf, wtoff2, b_off2, off_buf);
  deform_tile_kernel<<<nblk_df, 512, 0, stream>>>(d1_bf, off_buf, wtd2, b_d2, nullptr, d2_bf);
  off_tile_kernel<<<nblk_oc, 256, 0, stream>>>(ref_bf, d2_bf, wtoff3, b_off3, off_buf);
  deform_tile_kernel<<<nblk_df, 512, 0, stream>>>(d2_bf, off_buf, wtd3, b_d3, out, nullptr);
}

// Round 19
// 118.587 us; speedup vs baseline: 1.2370x; 1.0319x over previous
//
#include <hip/hip_runtime.h>
#include <hip/hip_bf16.h>

#define BB 4
#define CC 64
#define HH 128
#define WW 128
#define HW (HH * WW)
#define TOTPIX (BB * HW)  // 65536

typedef short bf16x8 __attribute__((ext_vector_type(8)));
typedef float f32x4 __attribute__((ext_vector_type(4)));

static __device__ __forceinline__ short f2bf(float f) {
  __hip_bfloat16 h = __float2bfloat16(f);
  return __builtin_bit_cast(short, h);
}
static __device__ __forceinline__ float bf2f(short s) {
  unsigned int u = ((unsigned int)(unsigned short)s) << 16;
  return __builtin_bit_cast(float, u);
}

// async 16B/lane global -> LDS (wave-uniform LDS base + lane*16)
static __device__ __forceinline__ void stage1k(const short* g, short* lds) {
  __builtin_amdgcn_global_load_lds(
      (const __attribute__((address_space(1))) unsigned int*)g,
      (__attribute__((address_space(3))) unsigned int*)lds, 16, 0, 0);
}

// Fused prep: blocks 0..1023 = NCHW f32 -> NHWC bf16 cast (ref+nbr);
// blocks 1024..1455 = weight prep for all 3 stages.
__global__ __launch_bounds__(256) void prep_all_kernel(
    const float* __restrict__ a, const float* __restrict__ b,
    short* __restrict__ oa, short* __restrict__ ob,
    const float* __restrict__ wd1, const float* __restrict__ wo1,
    short* __restrict__ wtd1, short* __restrict__ wtoff1,
    const float* __restrict__ wd2, const float* __restrict__ wo2,
    short* __restrict__ wtd2, short* __restrict__ wtoff2,
    const float* __restrict__ wd3, const float* __restrict__ wo3,
    short* __restrict__ wtd3, short* __restrict__ wtoff3) {
  __shared__ float tile[64][68];
  const int t = threadIdx.x;
  if (blockIdx.x < 1024) {
    const int bid = blockIdx.x;
    const int bb = bid >> 8;           // batch
    const int hw0 = (bid & 255) * 64;  // 64-px stripe
    for (int s = 0; s < 2; s++) {
      const float* src = s ? b : a;
      short* dst = s ? ob : oa;
      if (s) __syncthreads();
      {
        const int lp = t & 15;  // 16 lanes x float4 = 64 px
        for (int c = (t >> 4); c < 64; c += 16) {
          float4 v = *(const float4*)&src[((size_t)(bb * 64 + c)) * HW + hw0 + lp * 4];
          *(float4*)&tile[c][lp * 4] = v;
        }
      }
      __syncthreads();
      {
        const int px = t >> 2;
        const int seg = t & 3;
        bf16x8 s0, s1;
#pragma unroll
        for (int i = 0; i < 8; i++) s0[i] = f2bf(tile[seg * 16 + i][px]);
#pragma unroll
        for (int i = 0; i < 8; i++) s1[i] = f2bf(tile[seg * 16 + 8 + i][px]);
        short* dp = dst + ((size_t)(bid * 64 + px)) * 64 + seg * 16;
        *(bf16x8*)dp = s0;
        *(bf16x8*)(dp + 8) = s1;
      }
    }
  } else {
    const int pb = blockIdx.x - 1024;  // 0..431
    const int s = pb / 144;
    const float* wd = (s == 0) ? wd1 : (s == 1) ? wd2 : wd3;
    const float* wo = (s == 0) ? wo1 : (s == 1) ? wo2 : wo3;
    short* wtd = (s == 0) ? wtd1 : (s == 1) ? wtd2 : wtd3;
    short* wtoff = (s == 0) ? wtoff1 : (s == 1) ? wtoff2 : wtoff3;
    const int i = (pb % 144) * 256 + t;  // 0..36863
    const int j = i & 7, l = (i >> 3) & 63, f = i >> 9;
    {
      int ot = f & 3, cf = (f >> 2) & 1, k = f >> 3;
      int o = ot * 16 + (l & 15), c = cf * 32 + (l >> 4) * 8 + j;
      wtd[i] = f2bf(wd[(o * 64 + c) * 9 + k]);
    }
    {
      int ot = f & 1, ks = f >> 1;
      int cs = ks & 3, k = ks >> 2;
      int o = ot * 16 + (l & 15), c = cs * 32 + (l >> 4) * 8 + j;
      wtoff[i] = (o < 18) ? f2bf(wo[(o * 128 + c) * 9 + k]) : (short)0;
    }
  }
}

// ---------- LDS-tiled MFMA offset conv (r14) ----------
// Block = 256 thr = 4 row-waves; output 4x16 px, halo 6x24 px of BOTH
// tensors (36,864 B, chunk-swizzled). Planar f32 output off[18][TOTPIX].
__global__ __launch_bounds__(256, 4) void off_tile_kernel(
    const short* __restrict__ ref, const short* __restrict__ x2,
    const short* __restrict__ wtoff, const float* __restrict__ bias,
    float* __restrict__ out) {
  __shared__ short tile[2 * 6 * 24 * 64];  // [tensor][row][px][64ch]
  int bid = blockIdx.x;
  bid = (bid & 7) * (gridDim.x >> 3) + (bid >> 3);  // 1024 % 8 == 0
  const int tid = threadIdx.x;
  const int l = tid & 63;
  const int g = __builtin_amdgcn_readfirstlane(tid >> 6);  // row-group 0..3
  const int col = l & 15, quad = l >> 4;
  const int b = bid >> 8;
  const int rem = bid & 255;
  const int h0 = (rem >> 3) * 4;   // 32 row-tiles
  const int w0 = (rem & 7) * 16;   // 8 col-tiles
  const int oy = h0 - 1, ox = w0 - 1;
  const int h = h0 + g, w = w0 + col;
  const int pix = ((b << 7) + h) * WW + w;

  const short* srcs[2] = {ref + (size_t)b * (HW * 64), x2 + (size_t)b * (HW * 64)};

  {
    const int tc = l >> 3;  // px-in-chunk 0..7
    const int m = l & 7;    // dest slot
#pragma unroll
    for (int i = 0; i < 9; i++) {
      const int idx = g + i * 4;        // 0..35, wave-uniform
      const int t = idx / 18;
      const int rr = (idx % 18) / 3, seg = idx % 3;
      const int iy = min(max(oy + rr, 0), HH - 1);
      const int tcol = seg * 8 + tc;
      const int ix = min(max(ox + tcol, 0), WW - 1);
      const int sc = (m - tcol) & 7;
      stage1k(srcs[t] + (((iy << 7) + ix) << 6) + sc * 8,
              &tile[((t * 6 + rr) * 24 + seg * 8) << 6]);
    }
  }

  f32x4 acc0 = {0.f, 0.f, 0.f, 0.f}, acc1 = {0.f, 0.f, 0.f, 0.f};
  const bf16x8* wp = (const bf16x8*)wtoff + l;

  __syncthreads();  // tile staged

#pragma unroll
  for (int k = 0; k < 9; k++) {
    const int ky = k / 3, kx = k - ky * 3;
    const int hh = h + ky - 1, ww2 = w + kx - 1;
    const bool valid = (hh >= 0) & (hh < HH) & (ww2 >= 0) & (ww2 < WW);
    const int tr = g + ky;      // 0..5
    const int tcx = col + kx;   // 0..17
#pragma unroll
    for (int cs = 0; cs < 4; cs++) {
      const int t = cs >> 1;
      const int chunk = (cs & 1) * 4 + quad;  // 0..7 within pixel
      bf16x8 v = *(const bf16x8*)&tile[(((t * 6 + tr) * 24 + tcx) << 6) +
                                       (((chunk + tcx) & 7) << 3)];
      if (!valid) v = (bf16x8)(short)0;
      const int f = (k * 4 + cs) * 2;
      acc0 = __builtin_amdgcn_mfma_f32_16x16x32_bf16(wp[f * 64], v, acc0, 0, 0, 0);
      acc1 = __builtin_amdgcn_mfma_f32_16x16x32_bf16(wp[(f + 1) * 64], v, acc1, 0, 0, 0);
    }
  }

  // planar output: out[o][pix], coalesced 64B stores
#pragma unroll
  for (int r = 0; r < 4; r++)
    out[(quad * 4 + r) * TOTPIX + pix] = acc0[r] + bias[quad * 4 + r];
  if (quad == 0) {
    out[16 * TOTPIX + pix] = acc1[0] + bias[16];
    out[17 * TOTPIX + pix] = acc1[1] + bias[17];
  }
}

// ---------- LDS-tiled MFMA deformable conv (r14) ----------
// Block = 512 thr = 8 row-waves; output tile 8x16 px; halo 16x24 px
// (49KB, chunk-swizzled). Offsets read PLANAR (coalesced dword loads).
#define TH 16
#define TWP 24
__global__ __launch_bounds__(512, 4) void deform_tile_kernel(
    const short* __restrict__ x, const float* __restrict__ off,
    const short* __restrict__ wtd, const float* __restrict__ bias,
    float* __restrict__ outf, short* __restrict__ outb) {
  __shared__ short tile[TH * TWP * 64];  // 49152 B
  int bid = blockIdx.x;
  bid = (bid & 7) * (gridDim.x >> 3) + (bid >> 3);  // 512 % 8 == 0
  const int tid = threadIdx.x;
  const int l = tid & 63;
  const int wv = __builtin_amdgcn_readfirstlane(tid >> 6);  // 0..7
  const int col = l & 15, quad = l >> 4;
  const int b = bid >> 7;
  const int rem = bid & 127;
  const int h0 = (rem >> 3) * 8;   // 16 row-tiles
  const int w0 = (rem & 7) * 16;   // 8 col-tiles
  const int oy = h0 - 4, ox = w0 - 4;
  const int h = h0 + wv, w = w0 + col;
  const int pix = ((b << 7) + h) * WW + w;

  const short* xb = x + (size_t)b * (HW * 64);

  // ---- stage 16x24-px halo tile, chunk-swizzled source ----
  {
    const int tc = ((l >> 3) & 7);
    const int m = l & 7;
#pragma unroll
    for (int i = 0; i < 6; i++) {
      const int idx = wv + i * 8;        // 0..47
      const int r = idx / 3, seg = idx % 3;
      const int iy = min(max(oy + r, 0), HH - 1);
      const int tcol = seg * 8 + tc;
      const int ix = min(max(ox + tcol, 0), WW - 1);
      const int sc = (m - tcol) & 7;
      stage1k(xb + (((iy << 7) + ix) << 6) + sc * 8,
              &tile[((r * TWP + seg * 8) << 6)]);
    }
  }

  // planar offsets: off[j][pix], 18 coalesced dword loads
  float offv[18];
#pragma unroll
  for (int j = 0; j < 18; j++) offv[j] = off[j * TOTPIX + pix];

  f32x4 acc[4];
#pragma unroll
  for (int ot = 0; ot < 4; ot++)
#pragma unroll
    for (int r = 0; r < 4; r++) acc[ot][r] = 0.f;

  const int c0g = quad * 8;
  const bf16x8* wp = (const bf16x8*)wtd + l;

  __syncthreads();  // tile staged

#pragma unroll
  for (int k = 0; k < 9; k++) {
    const int ky = k / 3, kx = k - ky * 3;
    const float py = (float)(h - 1 + ky) + offv[2 * k];
    const float pxx = (float)(w - 1 + kx) + offv[2 * k + 1];
    const float y0f = floorf(py), x0f = floorf(pxx);
    const float ly = py - y0f, lx = pxx - x0f;
    const int y0 = (int)y0f, x0 = (int)x0f;
    const int y1 = y0 + 1, x1 = x0 + 1;
    float w00 = (1.f - ly) * (1.f - lx), w01 = (1.f - ly) * lx;
    float w10 = ly * (1.f - lx), w11 = ly * lx;
    if (y0 < 0 || y0 >= HH) { w00 = 0.f; w01 = 0.f; }
    if (y1 < 0 || y1 >= HH) { w10 = 0.f; w11 = 0.f; }
    if (x0 < 0 || x0 >= WW) { w00 = 0.f; w10 = 0.f; }
    if (x1 < 0 || x1 >= WW) { w01 = 0.f; w11 = 0.f; }
    const int cy0 = min(max(y0, 0), HH - 1), cy1 = min(max(y1, 0), HH - 1);
    const int cx0 = min(max(x0, 0), WW - 1), cx1 = min(max(x1, 0), WW - 1);

    const int ty0 = cy0 - oy, ty1 = cy1 - oy;
    const int tx0 = cx0 - ox, tx1 = cx1 - ox;
    const bool intile = (ty0 >= 0) & (ty1 < TH) & (tx0 >= 0) & (tx1 < TWP);

    bf16x8 v00a, v00b, v01a, v01b, v10a, v10b, v11a, v11b;
    if (__builtin_amdgcn_ballot_w64(intile) == ~0ull) {
      const int p00 = ((ty0 * TWP + tx0) << 6);
      const int p01 = ((ty0 * TWP + tx1) << 6);
      const int p10 = ((ty1 * TWP + tx0) << 6);
      const int p11 = ((ty1 * TWP + tx1) << 6);
      v00a = *(const bf16x8*)&tile[p00 + (((quad + tx0) & 7) << 3)];
      v00b = *(const bf16x8*)&tile[p00 + (((quad + 4 + tx0) & 7) << 3)];
      v01a = *(const bf16x8*)&tile[p01 + (((quad + tx1) & 7) << 3)];
      v01b = *(const bf16x8*)&tile[p01 + (((quad + 4 + tx1) & 7) << 3)];
      v10a = *(const bf16x8*)&tile[p10 + (((quad + tx0) & 7) << 3)];
      v10b = *(const bf16x8*)&tile[p10 + (((quad + 4 + tx0) & 7) << 3)];
      v11a = *(const bf16x8*)&tile[p11 + (((quad + tx1) & 7) << 3)];
      v11b = *(const bf16x8*)&tile[p11 + (((quad + 4 + tx1) & 7) << 3)];
    } else {
      const int p00 = ((cy0 * WW + cx0) << 6) + c0g;
      const int p01 = ((cy0 * WW + cx1) << 6) + c0g;
      const int p10 = ((cy1 * WW + cx0) << 6) + c0g;
      const int p11 = ((cy1 * WW + cx1) << 6) + c0g;
      v00a = *(const bf16x8*)(xb + p00);
      v00b = *(const bf16x8*)(xb + p00 + 32);
      v01a = *(const bf16x8*)(xb + p01);
      v01b = *(const bf16x8*)(xb + p01 + 32);
      v10a = *(const bf16x8*)(xb + p10);
      v10b = *(const bf16x8*)(xb + p10 + 32);
      v11a = *(const bf16x8*)(xb + p11);
      v11b = *(const bf16x8*)(xb + p11 + 32);
    }

    bf16x8 bs0, bs1;
#pragma unroll
    for (int j = 0; j < 8; j++) {
      float sa = bf2f(v00a[j]) * w00 + bf2f(v01a[j]) * w01 +
                 bf2f(v10a[j]) * w10 + bf2f(v11a[j]) * w11;
      bs0[j] = f2bf(sa);
      float sb = bf2f(v00b[j]) * w00 + bf2f(v01b[j]) * w01 +
                 bf2f(v10b[j]) * w10 + bf2f(v11b[j]) * w11;
      bs1[j] = f2bf(sb);
    }

    acc[0] = __builtin_amdgcn_mfma_f32_16x16x32_bf16(wp[(k * 8 + 0) * 64], bs0, acc[0], 0, 0, 0);
    acc[1] = __builtin_amdgcn_mfma_f32_16x16x32_bf16(wp[(k * 8 + 1) * 64], bs0, acc[1], 0, 0, 0);
    acc[2] = __builtin_amdgcn_mfma_f32_16x16x32_bf16(wp[(k * 8 + 2) * 64], bs0, acc[2], 0, 0, 0);
    acc[3] = __builtin_amdgcn_mfma_f32_16x16x32_bf16(wp[(k * 8 + 3) * 64], bs0, acc[3], 0, 0, 0);
    acc[0] = __builtin_amdgcn_mfma_f32_16x16x32_bf16(wp[(k * 8 + 4) * 64], bs1, acc[0], 0, 0, 0);
    acc[1] = __builtin_amdgcn_mfma_f32_16x16x32_bf16(wp[(k * 8 + 5) * 64], bs1, acc[1], 0, 0, 0);
    acc[2] = __builtin_amdgcn_mfma_f32_16x16x32_bf16(wp[(k * 8 + 6) * 64], bs1, acc[2], 0, 0, 0);
    acc[3] = __builtin_amdgcn_mfma_f32_16x16x32_bf16(wp[(k * 8 + 7) * 64], bs1, acc[3], 0, 0, 0);
  }

#pragma unroll
  for (int ot = 0; ot < 4; ot++)
#pragma unroll
    for (int r = 0; r < 4; r++)
      acc[ot][r] += bias[ot * 16 + quad * 4 + r];

  if (outb) {
#pragma unroll
    for (int ot = 0; ot < 4; ot++) {
      short4 sv;
      sv.x = f2bf(acc[ot][0]); sv.y = f2bf(acc[ot][1]);
      sv.z = f2bf(acc[ot][2]); sv.w = f2bf(acc[ot][3]);
      *(short4*)(outb + (size_t)pix * 64 + ot * 16 + quad * 4) = sv;
    }
  }
  if (outf) {
    const int hw = pix & (HW - 1);
#pragma unroll
    for (int ot = 0; ot < 4; ot++)
#pragma unroll
      for (int r = 0; r < 4; r++) {
        const int o = ot * 16 + quad * 4 + r;
        outf[(size_t)b * (CC * HW) + (size_t)o * HW + hw] = acc[ot][r];
      }
  }
}

extern "C" void kernel_launch(void* const* d_in, const int* in_sizes, int n_in,
                              void* d_out, int out_size, void* d_ws, size_t ws_size,
                              hipStream_t stream) {
  const float* ref    = (const float*)d_in[0];
  const float* nbr    = (const float*)d_in[1];
  const float* w_off1 = (const float*)d_in[2];
  const float* b_off1 = (const float*)d_in[3];
  const float* w_d1   = (const float*)d_in[4];
  const float* b_d1   = (const float*)d_in[5];
  const float* w_off2 = (const float*)d_in[6];
  const float* b_off2 = (const float*)d_in[7];
  const float* w_d2   = (const float*)d_in[8];
  const float* b_d2   = (const float*)d_in[9];
  const float* w_off3 = (const float*)d_in[10];
  const float* b_off3 = (const float*)d_in[11];
  const float* w_d3   = (const float*)d_in[12];
  const float* b_d3   = (const float*)d_in[13];

  float* out = (float*)d_out;
  char* ws = (char*)d_ws;
  float* off_buf = (float*)(ws);               // planar 18*65536*4 = 4,718,592 B
  short* ref_bf  = (short*)(ws + 5242880);     // 8,388,608 B each
  short* nbr_bf  = (short*)(ws + 13631488);
  short* d1_bf   = (short*)(ws + 22020096);
  short* d2_bf   = (short*)(ws + 30408704);
  short* wtd1    = (short*)(ws + 38797312);    // 73,728 B each
  short* wtd2    = (short*)(ws + 38871040);
  short* wtd3    = (short*)(ws + 38944768);
  short* wtoff1  = (short*)(ws + 39018496);
  short* wtoff2  = (short*)(ws + 39092224);
  short* wtoff3  = (short*)(ws + 39165952);

  prep_all_kernel<<<1456, 256, 0, stream>>>(
      ref, nbr, ref_bf, nbr_bf,
      w_d1, w_off1, wtd1, wtoff1,
      w_d2, w_off2, wtd2, wtoff2,
      w_d3, w_off3, wtd3, wtoff3);

  const int nblk_oc = BB * HW / 64;   // 1024 tiles of 4x16 px
  const int nblk_df = BB * HW / 128;  // 512 tiles of 8x16 px

  off_tile_kernel<<<nblk_oc, 256, 0, stream>>>(ref_bf, nbr_bf, wtoff1, b_off1, off_buf);
  deform_tile_kernel<<<nblk_df, 512, 0, stream>>>(nbr_bf, off_buf, wtd1, b_d1, nullptr, d1_bf);
  off_tile_kernel<<<nblk_oc, 256, 0, stream>>>(ref_bf, d1_bf, wtoff2, b_off2, off_buf);
  deform_tile_kernel<<<nblk_df, 512, 0, stream>>>(d1_bf, off_buf, wtd2, b_d2, nullptr, d2_bf);
  off_tile_kernel<<<nblk_oc, 256, 0, stream>>>(ref_bf, d2_bf, wtoff3, b_off3, off_buf);
  deform_tile_kernel<<<nblk_df, 512, 0, stream>>>(d2_bf, off_buf, wtd3, b_d3, out, nullptr);
}

// Round 20
// 111.113 us; speedup vs baseline: 1.3202x; 1.0673x over previous
//
#include <hip/hip_runtime.h>
#include <hip/hip_bf16.h>

#define BB 4
#define CC 64
#define HH 128
#define WW 128
#define HW (HH * WW)
#define TOTPIX (BB * HW)  // 65536

typedef short bf16x8 __attribute__((ext_vector_type(8)));
typedef float f32x4 __attribute__((ext_vector_type(4)));

static __device__ __forceinline__ short f2bf(float f) {
  __hip_bfloat16 h = __float2bfloat16(f);
  return __builtin_bit_cast(short, h);
}
static __device__ __forceinline__ float bf2f(short s) {
  unsigned int u = ((unsigned int)(unsigned short)s) << 16;
  return __builtin_bit_cast(float, u);
}

// async 16B/lane global -> LDS (wave-uniform LDS base + lane*16)
static __device__ __forceinline__ void stage1k(const short* g, short* lds) {
  __builtin_amdgcn_global_load_lds(
      (const __attribute__((address_space(1))) unsigned int*)g,
      (__attribute__((address_space(3))) unsigned int*)lds, 16, 0, 0);
}

// Fused prep: blocks 0..1023 = NCHW f32 -> NHWC bf16 cast (ref+nbr);
// blocks 1024..1455 = weight prep for all 3 stages.
__global__ __launch_bounds__(256) void prep_all_kernel(
    const float* __restrict__ a, const float* __restrict__ b,
    short* __restrict__ oa, short* __restrict__ ob,
    const float* __restrict__ wd1, const float* __restrict__ wo1,
    short* __restrict__ wtd1, short* __restrict__ wtoff1,
    const float* __restrict__ wd2, const float* __restrict__ wo2,
    short* __restrict__ wtd2, short* __restrict__ wtoff2,
    const float* __restrict__ wd3, const float* __restrict__ wo3,
    short* __restrict__ wtd3, short* __restrict__ wtoff3) {
  __shared__ float tile[64][68];
  const int t = threadIdx.x;
  if (blockIdx.x < 1024) {
    const int bid = blockIdx.x;
    const int bb = bid >> 8;           // batch
    const int hw0 = (bid & 255) * 64;  // 64-px stripe
    for (int s = 0; s < 2; s++) {
      const float* src = s ? b : a;
      short* dst = s ? ob : oa;
      if (s) __syncthreads();
      {
        const int lp = t & 15;  // 16 lanes x float4 = 64 px
        for (int c = (t >> 4); c < 64; c += 16) {
          float4 v = *(const float4*)&src[((size_t)(bb * 64 + c)) * HW + hw0 + lp * 4];
          *(float4*)&tile[c][lp * 4] = v;
        }
      }
      __syncthreads();
      {
        const int px = t >> 2;
        const int seg = t & 3;
        bf16x8 s0, s1;
#pragma unroll
        for (int i = 0; i < 8; i++) s0[i] = f2bf(tile[seg * 16 + i][px]);
#pragma unroll
        for (int i = 0; i < 8; i++) s1[i] = f2bf(tile[seg * 16 + 8 + i][px]);
        short* dp = dst + ((size_t)(bid * 64 + px)) * 64 + seg * 16;
        *(bf16x8*)dp = s0;
        *(bf16x8*)(dp + 8) = s1;
      }
    }
  } else {
    const int pb = blockIdx.x - 1024;  // 0..431
    const int s = pb / 144;
    const float* wd = (s == 0) ? wd1 : (s == 1) ? wd2 : wd3;
    const float* wo = (s == 0) ? wo1 : (s == 1) ? wo2 : wo3;
    short* wtd = (s == 0) ? wtd1 : (s == 1) ? wtd2 : wtd3;
    short* wtoff = (s == 0) ? wtoff1 : (s == 1) ? wtoff2 : wtoff3;
    const int i = (pb % 144) * 256 + t;  // 0..36863
    const int j = i & 7, l = (i >> 3) & 63, f = i >> 9;
    {
      int ot = f & 3, cf = (f >> 2) & 1, k = f >> 3;
      int o = ot * 16 + (l & 15), c = cf * 32 + (l >> 4) * 8 + j;
      wtd[i] = f2bf(wd[(o * 64 + c) * 9 + k]);
    }
    {
      int ot = f & 1, ks = f >> 1;
      int cs = ks & 3, k = ks >> 2;
      int o = ot * 16 + (l & 15), c = cs * 32 + (l >> 4) * 8 + j;
      wtoff[i] = (o < 18) ? f2bf(wo[(o * 128 + c) * 9 + k]) : (short)0;
    }
  }
}

// ---------- FUSED stage kernel: off-conv + deformable conv ----------
// Block = 512 thr = 8 row-waves; output tile 8x16 px.
// LDS: xt = 16x24 x-halo (49KB, deform tile; also serves off-conv's x reads,
//      which are a subset); rt = 10x24 ref-halo (30.7KB; off-conv only,
//      reused as offlds[128][20] f32 after phase 1).
// Phase 1 (off-conv): each wave computes all 18 offsets for its 16 px
//   (full K=128: cs 0,1 from rt; cs 2,3 from xt). C-layout lane (quad,col)
//   holds o=quad*4+r for px col -> write offlds, barrier, each lane reads
//   its own px's 18 offsets.
// Phase 2 (deform): byte-identical r14/r19 body, reading xt.
#define TH 16
#define TWP 24
#define RTH 10
__global__ __launch_bounds__(512, 2) void fused_stage_kernel(
    const short* __restrict__ ref, const short* __restrict__ x,
    const short* __restrict__ wtoff, const float* __restrict__ boff,
    const short* __restrict__ wtd, const float* __restrict__ bias,
    float* __restrict__ outf, short* __restrict__ outb) {
  __shared__ short xt[TH * TWP * 64];   // 49152 B
  __shared__ short rt[RTH * TWP * 64];  // 30720 B (-> offlds after phase 1)
  int bid = blockIdx.x;
  bid = (bid & 7) * (gridDim.x >> 3) + (bid >> 3);  // 512 % 8 == 0
  const int tid = threadIdx.x;
  const int l = tid & 63;
  const int wv = __builtin_amdgcn_readfirstlane(tid >> 6);  // 0..7
  const int col = l & 15, quad = l >> 4;
  const int b = bid >> 7;
  const int rem = bid & 127;
  const int h0 = (rem >> 3) * 8;   // 16 row-tiles
  const int w0 = (rem & 7) * 16;   // 8 col-tiles
  const int oy = h0 - 4, ox = w0 - 4;
  const int h = h0 + wv, w = w0 + col;
  const int pix = ((b << 7) + h) * WW + w;

  const short* xb = x + (size_t)b * (HW * 64);
  const short* rb = ref + (size_t)b * (HW * 64);

  // ---- stage xt: 16x24 x-halo (48 loads) + rt: 10x24 ref-halo (30 loads) ----
  {
    const int tc = ((l >> 3) & 7);
    const int m = l & 7;
#pragma unroll
    for (int i = 0; i < 6; i++) {
      const int idx = wv + i * 8;        // 0..47
      const int r = idx / 3, seg = idx % 3;
      const int iy = min(max(oy + r, 0), HH - 1);
      const int tcol = seg * 8 + tc;
      const int ix = min(max(ox + tcol, 0), WW - 1);
      const int sc = (m - tcol) & 7;
      stage1k(xb + (((iy << 7) + ix) << 6) + sc * 8,
              &xt[((r * TWP + seg * 8) << 6)]);
    }
#pragma unroll
    for (int i = 0; i < 4; i++) {
      const int idx = wv + i * 8;        // 0..31 (use 0..29)
      if (idx < 30) {
        const int r = idx / 3, seg = idx % 3;
        const int iy = min(max(h0 - 1 + r, 0), HH - 1);
        const int tcol = seg * 8 + tc;
        const int ix = min(max(ox + tcol, 0), WW - 1);
        const int sc = (m - tcol) & 7;
        stage1k(rb + (((iy << 7) + ix) << 6) + sc * 8,
                &rt[((r * TWP + seg * 8) << 6)]);
      }
    }
  }

  __syncthreads();  // both tiles staged

  // ================= phase 1: off-conv (all 18 offsets for this wave's px) ====
  f32x4 oacc0 = {0.f, 0.f, 0.f, 0.f}, oacc1 = {0.f, 0.f, 0.f, 0.f};
  {
    const bf16x8* wpo = (const bf16x8*)wtoff + l;
#pragma unroll
    for (int k = 0; k < 9; k++) {
      const int ky = k / 3, kx = k - ky * 3;
      const int hh = h + ky - 1, ww2 = w + kx - 1;
      const bool valid = (hh >= 0) & (hh < HH) & (ww2 >= 0) & (ww2 < WW);
      const int trr = wv + ky;        // ref-tile row (base h0-1): 0..9
      const int trx = wv + ky + 3;    // x-tile row (base h0-4): 3..12
      const int tcx = col + kx + 3;   // col (base w0-4): 3..20
#pragma unroll
      for (int cs = 0; cs < 4; cs++) {
        const int chunk = (cs & 1) * 4 + quad;
        const int sw = ((chunk + tcx) & 7) << 3;
        bf16x8 v;
        if (cs < 2)
          v = *(const bf16x8*)&rt[((trr * TWP + tcx) << 6) + sw];
        else
          v = *(const bf16x8*)&xt[((trx * TWP + tcx) << 6) + sw];
        if (!valid) v = (bf16x8)(short)0;
        const int f = (k * 4 + cs) * 2;
        oacc0 = __builtin_amdgcn_mfma_f32_16x16x32_bf16(wpo[f * 64], v, oacc0, 0, 0, 0);
        oacc1 = __builtin_amdgcn_mfma_f32_16x16x32_bf16(wpo[(f + 1) * 64], v, oacc1, 0, 0, 0);
      }
    }
  }

  __syncthreads();  // done reading rt; safe to overlay offlds

  float* offlds = (float*)rt;  // [128 px][20]
  {
    float* po = offlds + (wv * 16 + col) * 20;
#pragma unroll
    for (int r = 0; r < 4; r++) po[quad * 4 + r] = oacc0[r] + boff[quad * 4 + r];
    if (quad == 0) {
      po[16] = oacc1[0] + boff[16];
      po[17] = oacc1[1] + boff[17];
    }
  }
  __syncthreads();

  float offv[18];
#pragma unroll
  for (int j = 0; j < 18; j++) offv[j] = offlds[(wv * 16 + col) * 20 + j];

  // ================= phase 2: deformable conv (r14 body) =================
  f32x4 acc[4];
#pragma unroll
  for (int ot = 0; ot < 4; ot++)
#pragma unroll
    for (int r = 0; r < 4; r++) acc[ot][r] = 0.f;

  const int c0g = quad * 8;
  const bf16x8* wp = (const bf16x8*)wtd + l;

#pragma unroll
  for (int k = 0; k < 9; k++) {
    const int ky = k / 3, kx = k - ky * 3;
    const float py = (float)(h - 1 + ky) + offv[2 * k];
    const float pxx = (float)(w - 1 + kx) + offv[2 * k + 1];
    const float y0f = floorf(py), x0f = floorf(pxx);
    const float ly = py - y0f, lx = pxx - x0f;
    const int y0 = (int)y0f, x0 = (int)x0f;
    const int y1 = y0 + 1, x1 = x0 + 1;
    float w00 = (1.f - ly) * (1.f - lx), w01 = (1.f - ly) * lx;
    float w10 = ly * (1.f - lx), w11 = ly * lx;
    if (y0 < 0 || y0 >= HH) { w00 = 0.f; w01 = 0.f; }
    if (y1 < 0 || y1 >= HH) { w10 = 0.f; w11 = 0.f; }
    if (x0 < 0 || x0 >= WW) { w00 = 0.f; w10 = 0.f; }
    if (x1 < 0 || x1 >= WW) { w01 = 0.f; w11 = 0.f; }
    const int cy0 = min(max(y0, 0), HH - 1), cy1 = min(max(y1, 0), HH - 1);
    const int cx0 = min(max(x0, 0), WW - 1), cx1 = min(max(x1, 0), WW - 1);

    const int ty0 = cy0 - oy, ty1 = cy1 - oy;
    const int tx0 = cx0 - ox, tx1 = cx1 - ox;
    const bool intile = (ty0 >= 0) & (ty1 < TH) & (tx0 >= 0) & (tx1 < TWP);

    bf16x8 v00a, v00b, v01a, v01b, v10a, v10b, v11a, v11b;
    if (__builtin_amdgcn_ballot_w64(intile) == ~0ull) {
      const int p00 = ((ty0 * TWP + tx0) << 6);
      const int p01 = ((ty0 * TWP + tx1) << 6);
      const int p10 = ((ty1 * TWP + tx0) << 6);
      const int p11 = ((ty1 * TWP + tx1) << 6);
      v00a = *(const bf16x8*)&xt[p00 + (((quad + tx0) & 7) << 3)];
      v00b = *(const bf16x8*)&xt[p00 + (((quad + 4 + tx0) & 7) << 3)];
      v01a = *(const bf16x8*)&xt[p01 + (((quad + tx1) & 7) << 3)];
      v01b = *(const bf16x8*)&xt[p01 + (((quad + 4 + tx1) & 7) << 3)];
      v10a = *(const bf16x8*)&xt[p10 + (((quad + tx0) & 7) << 3)];
      v10b = *(const bf16x8*)&xt[p10 + (((quad + 4 + tx0) & 7) << 3)];
      v11a = *(const bf16x8*)&xt[p11 + (((quad + tx1) & 7) << 3)];
      v11b = *(const bf16x8*)&xt[p11 + (((quad + 4 + tx1) & 7) << 3)];
    } else {
      const int p00 = ((cy0 * WW + cx0) << 6) + c0g;
      const int p01 = ((cy0 * WW + cx1) << 6) + c0g;
      const int p10 = ((cy1 * WW + cx0) << 6) + c0g;
      const int p11 = ((cy1 * WW + cx1) << 6) + c0g;
      v00a = *(const bf16x8*)(xb + p00);
      v00b = *(const bf16x8*)(xb + p00 + 32);
      v01a = *(const bf16x8*)(xb + p01);
      v01b = *(const bf16x8*)(xb + p01 + 32);
      v10a = *(const bf16x8*)(xb + p10);
      v10b = *(const bf16x8*)(xb + p10 + 32);
      v11a = *(const bf16x8*)(xb + p11);
      v11b = *(const bf16x8*)(xb + p11 + 32);
    }

    bf16x8 bs0, bs1;
#pragma unroll
    for (int j = 0; j < 8; j++) {
      float sa = bf2f(v00a[j]) * w00 + bf2f(v01a[j]) * w01 +
                 bf2f(v10a[j]) * w10 + bf2f(v11a[j]) * w11;
      bs0[j] = f2bf(sa);
      float sb = bf2f(v00b[j]) * w00 + bf2f(v01b[j]) * w01 +
                 bf2f(v10b[j]) * w10 + bf2f(v11b[j]) * w11;
      bs1[j] = f2bf(sb);
    }

    acc[0] = __builtin_amdgcn_mfma_f32_16x16x32_bf16(wp[(k * 8 + 0) * 64], bs0, acc[0], 0, 0, 0);
    acc[1] = __builtin_amdgcn_mfma_f32_16x16x32_bf16(wp[(k * 8 + 1) * 64], bs0, acc[1], 0, 0, 0);
    acc[2] = __builtin_amdgcn_mfma_f32_16x16x32_bf16(wp[(k * 8 + 2) * 64], bs0, acc[2], 0, 0, 0);
    acc[3] = __builtin_amdgcn_mfma_f32_16x16x32_bf16(wp[(k * 8 + 3) * 64], bs0, acc[3], 0, 0, 0);
    acc[0] = __builtin_amdgcn_mfma_f32_16x16x32_bf16(wp[(k * 8 + 4) * 64], bs1, acc[0], 0, 0, 0);
    acc[1] = __builtin_amdgcn_mfma_f32_16x16x32_bf16(wp[(k * 8 + 5) * 64], bs1, acc[1], 0, 0, 0);
    acc[2] = __builtin_amdgcn_mfma_f32_16x16x32_bf16(wp[(k * 8 + 6) * 64], bs1, acc[2], 0, 0, 0);
    acc[3] = __builtin_amdgcn_mfma_f32_16x16x32_bf16(wp[(k * 8 + 7) * 64], bs1, acc[3], 0, 0, 0);
  }

#pragma unroll
  for (int ot = 0; ot < 4; ot++)
#pragma unroll
    for (int r = 0; r < 4; r++)
      acc[ot][r] += bias[ot * 16 + quad * 4 + r];

  if (outb) {
#pragma unroll
    for (int ot = 0; ot < 4; ot++) {
      short4 sv;
      sv.x = f2bf(acc[ot][0]); sv.y = f2bf(acc[ot][1]);
      sv.z = f2bf(acc[ot][2]); sv.w = f2bf(acc[ot][3]);
      *(short4*)(outb + (size_t)pix * 64 + ot * 16 + quad * 4) = sv;
    }
  }
  if (outf) {
    const int hw = pix & (HW - 1);
#pragma unroll
    for (int ot = 0; ot < 4; ot++)
#pragma unroll
      for (int r = 0; r < 4; r++) {
        const int o = ot * 16 + quad * 4 + r;
        outf[(size_t)b * (CC * HW) + (size_t)o * HW + hw] = acc[ot][r];
      }
  }
}

extern "C" void kernel_launch(void* const* d_in, const int* in_sizes, int n_in,
                              void* d_out, int out_size, void* d_ws, size_t ws_size,
                              hipStream_t stream) {
  const float* ref    = (const float*)d_in[0];
  const float* nbr    = (const float*)d_in[1];
  const float* w_off1 = (const float*)d_in[2];
  const float* b_off1 = (const float*)d_in[3];
  const float* w_d1   = (const float*)d_in[4];
  const float* b_d1   = (const float*)d_in[5];
  const float* w_off2 = (const float*)d_in[6];
  const float* b_off2 = (const float*)d_in[7];
  const float* w_d2   = (const float*)d_in[8];
  const float* b_d2   = (const float*)d_in[9];
  const float* w_off3 = (const float*)d_in[10];
  const float* b_off3 = (const float*)d_in[11];
  const float* w_d3   = (const float*)d_in[12];
  const float* b_d3   = (const float*)d_in[13];

  float* out = (float*)d_out;
  char* ws = (char*)d_ws;
  short* ref_bf  = (short*)(ws + 5242880);     // 8,388,608 B each
  short* nbr_bf  = (short*)(ws + 13631488);
  short* d1_bf   = (short*)(ws + 22020096);
  short* d2_bf   = (short*)(ws + 30408704);
  short* wtd1    = (short*)(ws + 38797312);    // 73,728 B each
  short* wtd2    = (short*)(ws + 38871040);
  short* wtd3    = (short*)(ws + 38944768);
  short* wtoff1  = (short*)(ws + 39018496);
  short* wtoff2  = (short*)(ws + 39092224);
  short* wtoff3  = (short*)(ws + 39165952);

  prep_all_kernel<<<1456, 256, 0, stream>>>(
      ref, nbr, ref_bf, nbr_bf,
      w_d1, w_off1, wtd1, wtoff1,
      w_d2, w_off2, wtd2, wtoff2,
      w_d3, w_off3, wtd3, wtoff3);

  const int nblk = BB * HW / 128;  // 512 tiles of 8x16 px

  fused_stage_kernel<<<nblk, 512, 0, stream>>>(
      ref_bf, nbr_bf, wtoff1, b_off1, wtd1, b_d1, nullptr, d1_bf);
  fused_stage_kernel<<<nblk, 512, 0, stream>>>(
      ref_bf, d1_bf, wtoff2, b_off2, wtd2, b_d2, nullptr, d2_bf);
  fused_stage_kernel<<<nblk, 512, 0, stream>>>(
      ref_bf, d2_bf, wtoff3, b_off3, wtd3, b_d3, out, nullptr);
}